// Round 1
// baseline (682.559 us; speedup 1.0000x reference)
//
#include <hip/hip_runtime.h>
#include <stdint.h>

#define NTOK 8192
#define DIMD 1024
#define NEXP 8
#define DFFD 4096
#define CAPD 1280

typedef _Float16 half8_t __attribute__((ext_vector_type(8)));
typedef _Float16 half4_t __attribute__((ext_vector_type(4)));
typedef float float4_t __attribute__((ext_vector_type(4)));

typedef const __attribute__((address_space(1))) uint32_t* gas_ptr_t;
typedef __attribute__((address_space(3))) uint32_t* las_ptr_t;

__device__ __forceinline__ void async_ld16(void* lds, const void* g) {
  __builtin_amdgcn_global_load_lds((gas_ptr_t)g, (las_ptr_t)lds, 16, 0, 0);
}

// Counted-vmcnt barrier: waits only the OLDEST outstanding global_load_lds
// groups, keeps the newest 4 in flight across the workgroup barrier.
// s_barrier lives INSIDE the asm so no compiler-inserted vmcnt(0) drain and
// no code motion across it (memory clobber).
__device__ __forceinline__ void wait4_barrier() {
  asm volatile("s_waitcnt vmcnt(4)\n\ts_barrier" ::: "memory");
}
__device__ __forceinline__ void wait0_barrier() {
  asm volatile("s_waitcnt vmcnt(0)\n\ts_barrier" ::: "memory");
}

__device__ __forceinline__ float gelu_f(float v) {
  // tanh-approx gelu (JAX default approximate=True)
  float u = 0.7978845608028654f * (v + 0.044715f * v * v * v);
  float t = 1.f - 2.f / (__expf(2.f * u) + 1.f);
  return 0.5f * v * (1.f + t);
}

// ---------------- router: logits, softmax, gate, argmax ----------------
__global__ __launch_bounds__(256) void router_kernel(
    const float* __restrict__ x, const float* __restrict__ Wr,
    int* __restrict__ eidx, float* __restrict__ gate,
    float* __restrict__ probs_tok) {
  __shared__ float wrt[NEXP * DIMD];  // transposed [e][d]
  int tid = threadIdx.x;
  for (int i = tid; i < NEXP * DIMD; i += 256) {
    int d = i >> 3, e = i & 7;
    wrt[e * DIMD + d] = Wr[i];
  }
  __syncthreads();
  int wave = tid >> 6, lane = tid & 63;
  int tok = blockIdx.x * 4 + wave;
  float acc[NEXP];
#pragma unroll
  for (int e = 0; e < NEXP; e++) acc[e] = 0.f;
  const float* xr = x + (size_t)tok * DIMD;
#pragma unroll
  for (int i = 0; i < DIMD / 64; i++) {
    int d = lane + i * 64;
    float xv = xr[d];
#pragma unroll
    for (int e = 0; e < NEXP; e++) acc[e] += xv * wrt[e * DIMD + d];
  }
#pragma unroll
  for (int off = 32; off >= 1; off >>= 1) {
#pragma unroll
    for (int e = 0; e < NEXP; e++) acc[e] += __shfl_xor(acc[e], off, 64);
  }
  float m = acc[0];
#pragma unroll
  for (int e = 1; e < NEXP; e++) m = fmaxf(m, acc[e]);
  float p[NEXP];
  float s = 0.f;
#pragma unroll
  for (int e = 0; e < NEXP; e++) { p[e] = __expf(acc[e] - m); s += p[e]; }
  float inv = 1.f / s;
  int ei = 0;
  float best = acc[0];
#pragma unroll
  for (int e = 1; e < NEXP; e++) { if (acc[e] > best) { best = acc[e]; ei = e; } }
  if (lane == 0) {
    eidx[tok] = ei;
    gate[tok] = p[ei] * inv;
    float4 pa = make_float4(p[0] * inv, p[1] * inv, p[2] * inv, p[3] * inv);
    float4 pb = make_float4(p[4] * inv, p[5] * inv, p[6] * inv, p[7] * inv);
    float4* pp = (float4*)(probs_tok + (size_t)tok * 8);
    pp[0] = pa;
    pp[1] = pb;
  }
}

// ---------------- ordered capacity scan (single block) ----------------
__global__ __launch_bounds__(256) void scan_kernel(
    const int* __restrict__ eidx, const float* __restrict__ gate,
    const float* __restrict__ probs_tok, float* __restrict__ gatef,
    int* __restrict__ s2t, int* __restrict__ kept_out,
    float* __restrict__ aux_out) {
  __shared__ int cnt[256][NEXP];
  __shared__ float ps[256][NEXP];
  __shared__ int tot[NEXP];
  __shared__ float psum_s[NEXP];
  int tid = threadIdx.x;
  for (int i = tid; i < NEXP * CAPD; i += 256) s2t[i] = NTOK;
  float pa[NEXP];
#pragma unroll
  for (int k = 0; k < NEXP; k++) pa[k] = 0.f;
  for (int b = tid; b < NTOK; b += 256) {
    const float4* p = (const float4*)(probs_tok + (size_t)b * 8);
    float4 v0 = p[0], v1 = p[1];
    pa[0] += v0.x; pa[1] += v0.y; pa[2] += v0.z; pa[3] += v0.w;
    pa[4] += v1.x; pa[5] += v1.y; pa[6] += v1.z; pa[7] += v1.w;
  }
#pragma unroll
  for (int k = 0; k < NEXP; k++) ps[tid][k] = pa[k];
  int c[NEXP];
#pragma unroll
  for (int k = 0; k < NEXP; k++) c[k] = 0;
  int base = tid * 32;
  for (int i = 0; i < 32; i++) {
    int e = eidx[base + i];
#pragma unroll
    for (int k = 0; k < NEXP; k++) c[k] += (e == k);
  }
#pragma unroll
  for (int k = 0; k < NEXP; k++) cnt[tid][k] = c[k];
  __syncthreads();
  if (tid < NEXP) {
    int run = 0;
    for (int j = 0; j < 256; j++) { int v = cnt[j][tid]; cnt[j][tid] = run; run += v; }
    tot[tid] = run;
    float s = 0.f;
    for (int j = 0; j < 256; j++) s += ps[j][tid];
    psum_s[tid] = s;
  }
  __syncthreads();
  int off[NEXP];
#pragma unroll
  for (int k = 0; k < NEXP; k++) off[k] = cnt[tid][k];
  for (int i = 0; i < 32; i++) {
    int t2 = base + i;
    int e = eidx[t2];
    int pos = 0;
#pragma unroll
    for (int k = 0; k < NEXP; k++) pos += (e == k) ? off[k] : 0;
    bool kept = pos < CAPD;
    gatef[t2] = kept ? gate[t2] : 0.f;
    kept_out[t2] = kept ? 1 : 0;
    if (kept) s2t[e * CAPD + pos] = t2;
#pragma unroll
    for (int k = 0; k < NEXP; k++) off[k] += (e == k);
  }
  if (tid == 0) {
    float a = 0.f;
    for (int e = 0; e < NEXP; e++) {
      float tpe = (float)(tot[e] < CAPD ? tot[e] : CAPD);
      a += tpe * psum_s[e];
    }
    aux_out[0] = 0.01f * (float)NEXP * a / ((float)NTOK * (float)NTOK);
  }
}

// -------- transpose + fp32->fp16 convert: in [E][R][C] -> out [E][C][R] --------
__global__ __launch_bounds__(256) void transpose_cvt_kernel(
    const float* __restrict__ in, _Float16* __restrict__ out, int R, int C) {
  __shared__ float tile[64][65];
  int nC = C >> 6, nR = R >> 6;
  int b = blockIdx.x;
  int e = b / (nR * nC);
  int rem = b % (nR * nC);
  int rt = rem / nC, ct = rem % nC;
  int tid = threadIdx.x;
  int r = tid >> 2, c0 = (tid & 3) * 16;
  const float* ip = in + (size_t)e * R * C + (size_t)(rt * 64 + r) * C + ct * 64 + c0;
#pragma unroll
  for (int j = 0; j < 4; j++) {
    float4 v = *(const float4*)(ip + j * 4);
    tile[r][c0 + j * 4 + 0] = v.x;
    tile[r][c0 + j * 4 + 1] = v.y;
    tile[r][c0 + j * 4 + 2] = v.z;
    tile[r][c0 + j * 4 + 3] = v.w;
  }
  __syncthreads();
  int c = tid >> 2, r0 = (tid & 3) * 16;
  half8_t o0, o1;
#pragma unroll
  for (int j = 0; j < 8; j++) {
    o0[j] = (_Float16)tile[r0 + j][c];
    o1[j] = (_Float16)tile[r0 + 8 + j][c];
  }
  _Float16* op = out + (size_t)e * C * R + (size_t)(ct * 64 + c) * R + rt * 64 + r0;
  *(half8_t*)op = o0;
  *(half8_t*)(op + 8) = o1;
}

// ---------------- gather routed tokens to fp16 [E][CAP][D] ----------------
__global__ __launch_bounds__(256) void gather_kernel(
    const float* __restrict__ x, const int* __restrict__ s2t,
    _Float16* __restrict__ gxb) {
  int slot = blockIdx.x;
  int tok = s2t[slot];
  int tid = threadIdx.x;
  half4_t o;
  if (tok < NTOK) {
    float4 v = *(const float4*)(x + (size_t)tok * DIMD + tid * 4);
    o[0] = (_Float16)v.x; o[1] = (_Float16)v.y;
    o[2] = (_Float16)v.z; o[3] = (_Float16)v.w;
  } else {
    o[0] = o[1] = o[2] = o[3] = (_Float16)0.f;
  }
  *(half4_t*)(gxb + (size_t)slot * DIMD + tid * 4) = o;
}

// ---------------- passthrough for dropped tokens only ----------------
__global__ __launch_bounds__(256) void passthru_kernel(
    const float* __restrict__ x, const int* __restrict__ kept,
    float* __restrict__ out) {
  int tok = blockIdx.x;
  if (kept[tok]) return;
  int tid = threadIdx.x;
  *(float4*)(out + (size_t)tok * DIMD + tid * 4) =
      *(const float4*)(x + (size_t)tok * DIMD + tid * 4);
}

// ---------------- 256x256 deep-pipelined MFMA GEMM core ----------------
// C[256x256] += A[256xK] * B^T[256xK], 512 threads = 8 waves (2Mx4N),
// per-wave 128x64 output (8x4 16x16 frags). BK=32.
// LDS: 4-slot ring, slot = A[256][32] + B[256][32] f16 = 32 KB -> 128 KB total.
// Depth-2 prefetch: iter t stages tile t+2 (slot (t+2)&3, freed at barrier
// ending iter t-1; its last readers finished iter t-2). Per-iter sync is
// s_waitcnt vmcnt(4) + raw s_barrier: tile t+1's 4 loads are the oldest of
// 8 outstanding -> landed; tile t+2's 4 stay in flight ACROSS the barrier
// (never vmcnt(0) in steady state).
// XOR swizzle: 16B chunk q stored at q ^ ((row>>1)&3)  (R1-verified
// conflict-free for 64B-row-stride tiles); global source pre-swizzled since
// global_load_lds writes linearly.
template <int KD>
__device__ __forceinline__ void gemm_core256(const _Float16* __restrict__ A,
                                             const _Float16* __restrict__ B,
                                             _Float16* buf, float4_t acc[8][4]) {
  const int tid = threadIdx.x;  // 0..511
  const _Float16* gp[4];
  int lofs[4];
#pragma unroll
  for (int j = 0; j < 2; ++j) {
    int elem = j * 4096 + tid * 8;   // halfs within a 256x32 matrix
    int row = elem >> 5;
    int q = (elem >> 3) & 3;
    int qs = q ^ ((row >> 1) & 3);   // inverse-swizzled source chunk
    gp[j] = A + (size_t)row * KD + qs * 8;
    gp[2 + j] = B + (size_t)row * KD + qs * 8;
    lofs[j] = elem;          // A region of slot
    lofs[2 + j] = 8192 + elem;  // B region of slot
  }
  const int lane = tid & 63;
  const int wm = ((tid >> 6) >> 2) * 128;  // wave row offset {0,128}
  const int wn = ((tid >> 6) & 3) * 64;    // wave col offset {0,64,128,192}
  const int lr = lane & 15, lk8 = lane >> 4;
  const int ko = (lk8 ^ ((lr >> 1) & 3)) * 8;
  constexpr int KT = KD / 32;
  // prologue: stage tile 0 -> slot 0, tile 1 -> slot 1
#pragma unroll
  for (int j = 0; j < 4; ++j) async_ld16(buf + lofs[j], gp[j]);
#pragma unroll
  for (int j = 0; j < 4; ++j) {
    async_ld16(buf + 16384 + lofs[j], gp[j] + 32);
    gp[j] += 64;
  }
  wait4_barrier();  // tile 0 landed everywhere; tile 1 still in flight
#pragma unroll 1
  for (int t = 0; t < KT; ++t) {
    if (t + 2 < KT) {
      _Float16* dst = buf + ((t + 2) & 3) * 16384;
#pragma unroll
      for (int j = 0; j < 4; ++j) { async_ld16(dst + lofs[j], gp[j]); gp[j] += 32; }
    }
    const _Float16* As = buf + (t & 3) * 16384;
    const _Float16* Bs = As + 8192;
    half8_t a[8], b[4];
#pragma unroll
    for (int i = 0; i < 4; ++i)
      b[i] = *(const half8_t*)(Bs + (wn + i * 16 + lr) * 32 + ko);
#pragma unroll
    for (int i = 0; i < 8; ++i)
      a[i] = *(const half8_t*)(As + (wm + i * 16 + lr) * 32 + ko);
    __builtin_amdgcn_s_setprio(1);
#pragma unroll
    for (int mi = 0; mi < 8; ++mi)
#pragma unroll
      for (int ni = 0; ni < 4; ++ni)
        acc[mi][ni] =
            __builtin_amdgcn_mfma_f32_16x16x32_f16(a[mi], b[ni], acc[mi][ni], 0, 0, 0);
    __builtin_amdgcn_s_setprio(0);
    if (t + 2 < KT) wait4_barrier(); else wait0_barrier();
  }
}

// ---------------- GEMM1: h = gelu(gx @ W1 + b1), fp16 out ----------------
__global__ __launch_bounds__(512, 2) void gemm1_kernel(
    const _Float16* __restrict__ gxb, const _Float16* __restrict__ w1t,
    const float* __restrict__ b1, _Float16* __restrict__ hb) {
  __shared__ __align__(16) _Float16 buf[65536];  // 128 KB ring
  int blk = blockIdx.x;
  int e = blk / 80;             // 5 M-tiles x 16 N-tiles per expert
  int rem = blk % 80;
  int mb = rem / 16, nb = rem % 16;  // nb fastest: consecutive blocks share A panel (L2)
  const _Float16* A = gxb + (size_t)e * CAPD * DIMD + (size_t)mb * 256 * DIMD;
  const _Float16* B = w1t + (size_t)e * DFFD * DIMD + (size_t)nb * 256 * DIMD;
  float4_t acc[8][4];
#pragma unroll
  for (int mi = 0; mi < 8; ++mi)
#pragma unroll
    for (int ni = 0; ni < 4; ++ni) acc[mi][ni] = (float4_t){0.f, 0.f, 0.f, 0.f};
  gemm_core256<DIMD>(A, B, buf, acc);
  const int tid = threadIdx.x;
  const int lane = tid & 63;
  const int wm = ((tid >> 6) >> 2) * 128, wn = ((tid >> 6) & 3) * 64;
  const int l15 = lane & 15, q4 = (lane >> 4) * 4;
  float bias[4];
#pragma unroll
  for (int ni = 0; ni < 4; ++ni) bias[ni] = b1[e * DFFD + nb * 256 + wn + ni * 16 + l15];
  _Float16* hrow = hb + (size_t)e * CAPD * DFFD + (size_t)(mb * 256) * DFFD + nb * 256;
#pragma unroll
  for (int mi = 0; mi < 8; ++mi)
#pragma unroll
    for (int ni = 0; ni < 4; ++ni)
#pragma unroll
      for (int r = 0; r < 4; ++r) {
        int row = wm + mi * 16 + q4 + r;
        int col = wn + ni * 16 + l15;
        float v = acc[mi][ni][r] + bias[ni];
        hrow[(size_t)row * DFFD + col] = (_Float16)gelu_f(v);
      }
}

// ---------------- GEMM2: final[tok] = (h @ W2 + b2) * gate ----------------
__global__ __launch_bounds__(512, 2) void gemm2_kernel(
    const _Float16* __restrict__ hb, const _Float16* __restrict__ w2t,
    const float* __restrict__ b2, const int* __restrict__ s2t,
    const float* __restrict__ gatef, float* __restrict__ outp) {
  __shared__ __align__(16) _Float16 buf[65536];  // 128 KB ring
  __shared__ int tok_s[256];
  __shared__ float gate_s[256];
  int blk = blockIdx.x;
  int e = blk / 20;             // 5 M-tiles x 4 N-tiles per expert
  int rem = blk % 20;
  int mb = rem / 4, nb = rem % 4;
  int tid = threadIdx.x;
  if (tid < 256) {
    int tok = s2t[e * CAPD + mb * 256 + tid];
    tok_s[tid] = tok;
    gate_s[tid] = (tok < NTOK) ? gatef[tok] : 0.f;
  }
  __syncthreads();  // drains all vmem before the counted-vmcnt core
  const _Float16* A = hb + (size_t)e * CAPD * DFFD + (size_t)mb * 256 * DFFD;
  const _Float16* B = w2t + (size_t)e * DIMD * DFFD + (size_t)nb * 256 * DFFD;
  float4_t acc[8][4];
#pragma unroll
  for (int mi = 0; mi < 8; ++mi)
#pragma unroll
    for (int ni = 0; ni < 4; ++ni) acc[mi][ni] = (float4_t){0.f, 0.f, 0.f, 0.f};
  gemm_core256<DFFD>(A, B, buf, acc);
  const int lane = tid & 63;
  const int wm = ((tid >> 6) >> 2) * 128, wn = ((tid >> 6) & 3) * 64;
  const int l15 = lane & 15, q4 = (lane >> 4) * 4;
  float bias[4];
#pragma unroll
  for (int ni = 0; ni < 4; ++ni) bias[ni] = b2[e * DIMD + nb * 256 + wn + ni * 16 + l15];
#pragma unroll
  for (int mi = 0; mi < 8; ++mi)
#pragma unroll
    for (int r = 0; r < 4; ++r) {
      int row = wm + mi * 16 + q4 + r;
      int tok = tok_s[row];
      float g = gate_s[row];
      if (tok < NTOK) {
#pragma unroll
        for (int ni = 0; ni < 4; ++ni) {
          int col = nb * 256 + wn + ni * 16 + l15;
          outp[(size_t)tok * DIMD + col] = (acc[mi][ni][r] + bias[ni]) * g;
        }
      }
    }
}

extern "C" void kernel_launch(void* const* d_in, const int* in_sizes, int n_in,
                              void* d_out, int out_size, void* d_ws, size_t ws_size,
                              hipStream_t stream) {
  const float* x  = (const float*)d_in[0];
  const float* Wr = (const float*)d_in[1];
  const float* W1 = (const float*)d_in[2];
  const float* b1 = (const float*)d_in[3];
  const float* W2 = (const float*)d_in[4];
  const float* b2 = (const float*)d_in[5];
  float* out = (float*)d_out;

  char* ws = (char*)d_ws;
  float* probs_tok = (float*)ws;                        // 256 KB
  int* eidx   = (int*)(ws + 262144);                    // 32 KB
  float* gate = (float*)(ws + 262144 + 32768);          // 32 KB
  float* gatef = (float*)(ws + 262144 + 65536);         // 32 KB
  int* s2t    = (int*)(ws + 262144 + 98304);            // 40 KB
  int* kept   = (int*)(ws + 262144 + 139264);           // 32 KB
  char* big = ws + 448 * 1024;
  _Float16* gxb = (_Float16*)big;                                   // 20 MB
  _Float16* wt  = (_Float16*)(big + 20971520);                      // 64 MB (W1t, then W2t)
  _Float16* hb  = (_Float16*)(big + 20971520 + 67108864);           // 80 MB

  router_kernel<<<NTOK / 4, 256, 0, stream>>>(x, Wr, eidx, gate, probs_tok);
  scan_kernel<<<1, 256, 0, stream>>>(eidx, gate, probs_tok, gatef, s2t, kept,
                                     out + (size_t)NTOK * DIMD);
  transpose_cvt_kernel<<<NEXP * 16 * 64, 256, 0, stream>>>(W1, wt, DIMD, DFFD);
  gather_kernel<<<NEXP * CAPD, 256, 0, stream>>>(x, s2t, gxb);
  passthru_kernel<<<NTOK, 256, 0, stream>>>(x, kept, out);
  gemm1_kernel<<<NEXP * 5 * 16, 512, 0, stream>>>(gxb, wt, b1, hb);
  transpose_cvt_kernel<<<NEXP * 64 * 16, 256, 0, stream>>>(W2, wt, DFFD, DIMD);
  gemm2_kernel<<<NEXP * 5 * 4, 512, 0, stream>>>(hb, wt, b2, s2t, gatef, out);
}

// Round 3
// 645.111 us; speedup vs baseline: 1.0580x; 1.0580x over previous
//
#include <hip/hip_runtime.h>
#include <stdint.h>

#define NTOK 8192
#define DIMD 1024
#define NEXP 8
#define DFFD 4096
#define CAPD 1280

typedef _Float16 half8_t __attribute__((ext_vector_type(8)));
typedef _Float16 half4_t __attribute__((ext_vector_type(4)));
typedef float float4_t __attribute__((ext_vector_type(4)));

typedef const __attribute__((address_space(1))) uint32_t* gas_ptr_t;
typedef __attribute__((address_space(3))) uint32_t* las_ptr_t;

__device__ __forceinline__ void async_ld16(void* lds, const void* g) {
  __builtin_amdgcn_global_load_lds((gas_ptr_t)g, (las_ptr_t)lds, 16, 0, 0);
}

// Counted-vmcnt barrier: waits only the OLDEST outstanding global_load_lds
// groups, keeps the newest 4 in flight across the workgroup barrier.
__device__ __forceinline__ void wait4_barrier() {
  asm volatile("s_waitcnt vmcnt(4)\n\ts_barrier" ::: "memory");
}
__device__ __forceinline__ void wait0_barrier() {
  asm volatile("s_waitcnt vmcnt(0)\n\ts_barrier" ::: "memory");
}

__device__ __forceinline__ float gelu_f(float v) {
  // tanh-approx gelu (JAX default approximate=True)
  float u = 0.7978845608028654f * (v + 0.044715f * v * v * v);
  float t = 1.f - 2.f / (__expf(2.f * u) + 1.f);
  return 0.5f * v * (1.f + t);
}

// ---------------- router: logits, softmax, gate, argmax ----------------
__global__ __launch_bounds__(256) void router_kernel(
    const float* __restrict__ x, const float* __restrict__ Wr,
    int* __restrict__ eidx, float* __restrict__ gate,
    float* __restrict__ probs_tok) {
  __shared__ float wrt[NEXP * DIMD];  // transposed [e][d]
  int tid = threadIdx.x;
  for (int i = tid; i < NEXP * DIMD; i += 256) {
    int d = i >> 3, e = i & 7;
    wrt[e * DIMD + d] = Wr[i];
  }
  __syncthreads();
  int wave = tid >> 6, lane = tid & 63;
  int tok = blockIdx.x * 4 + wave;
  float acc[NEXP];
#pragma unroll
  for (int e = 0; e < NEXP; e++) acc[e] = 0.f;
  const float* xr = x + (size_t)tok * DIMD;
#pragma unroll
  for (int i = 0; i < DIMD / 64; i++) {
    int d = lane + i * 64;
    float xv = xr[d];
#pragma unroll
    for (int e = 0; e < NEXP; e++) acc[e] += xv * wrt[e * DIMD + d];
  }
#pragma unroll
  for (int off = 32; off >= 1; off >>= 1) {
#pragma unroll
    for (int e = 0; e < NEXP; e++) acc[e] += __shfl_xor(acc[e], off, 64);
  }
  float m = acc[0];
#pragma unroll
  for (int e = 1; e < NEXP; e++) m = fmaxf(m, acc[e]);
  float p[NEXP];
  float s = 0.f;
#pragma unroll
  for (int e = 0; e < NEXP; e++) { p[e] = __expf(acc[e] - m); s += p[e]; }
  float inv = 1.f / s;
  int ei = 0;
  float best = acc[0];
#pragma unroll
  for (int e = 1; e < NEXP; e++) { if (acc[e] > best) { best = acc[e]; ei = e; } }
  if (lane == 0) {
    eidx[tok] = ei;
    gate[tok] = p[ei] * inv;
    float4 pa = make_float4(p[0] * inv, p[1] * inv, p[2] * inv, p[3] * inv);
    float4 pb = make_float4(p[4] * inv, p[5] * inv, p[6] * inv, p[7] * inv);
    float4* pp = (float4*)(probs_tok + (size_t)tok * 8);
    pp[0] = pa;
    pp[1] = pb;
  }
}

// ---------------- ordered capacity scan (single block) ----------------
__global__ __launch_bounds__(256) void scan_kernel(
    const int* __restrict__ eidx, const float* __restrict__ gate,
    const float* __restrict__ probs_tok, float* __restrict__ gatef,
    int* __restrict__ s2t, int* __restrict__ kept_out,
    float* __restrict__ aux_out) {
  __shared__ int cnt[256][NEXP];
  __shared__ float ps[256][NEXP];
  __shared__ int tot[NEXP];
  __shared__ float psum_s[NEXP];
  int tid = threadIdx.x;
  for (int i = tid; i < NEXP * CAPD; i += 256) s2t[i] = NTOK;
  float pa[NEXP];
#pragma unroll
  for (int k = 0; k < NEXP; k++) pa[k] = 0.f;
  for (int b = tid; b < NTOK; b += 256) {
    const float4* p = (const float4*)(probs_tok + (size_t)b * 8);
    float4 v0 = p[0], v1 = p[1];
    pa[0] += v0.x; pa[1] += v0.y; pa[2] += v0.z; pa[3] += v0.w;
    pa[4] += v1.x; pa[5] += v1.y; pa[6] += v1.z; pa[7] += v1.w;
  }
#pragma unroll
  for (int k = 0; k < NEXP; k++) ps[tid][k] = pa[k];
  int c[NEXP];
#pragma unroll
  for (int k = 0; k < NEXP; k++) c[k] = 0;
  int base = tid * 32;
  for (int i = 0; i < 32; i++) {
    int e = eidx[base + i];
#pragma unroll
    for (int k = 0; k < NEXP; k++) c[k] += (e == k);
  }
#pragma unroll
  for (int k = 0; k < NEXP; k++) cnt[tid][k] = c[k];
  __syncthreads();
  if (tid < NEXP) {
    int run = 0;
    for (int j = 0; j < 256; j++) { int v = cnt[j][tid]; cnt[j][tid] = run; run += v; }
    tot[tid] = run;
    float s = 0.f;
    for (int j = 0; j < 256; j++) s += ps[j][tid];
    psum_s[tid] = s;
  }
  __syncthreads();
  int off[NEXP];
#pragma unroll
  for (int k = 0; k < NEXP; k++) off[k] = cnt[tid][k];
  for (int i = 0; i < 32; i++) {
    int t2 = base + i;
    int e = eidx[t2];
    int pos = 0;
#pragma unroll
    for (int k = 0; k < NEXP; k++) pos += (e == k) ? off[k] : 0;
    bool kept = pos < CAPD;
    gatef[t2] = kept ? gate[t2] : 0.f;
    kept_out[t2] = kept ? 1 : 0;
    if (kept) s2t[e * CAPD + pos] = t2;
#pragma unroll
    for (int k = 0; k < NEXP; k++) off[k] += (e == k);
  }
  if (tid == 0) {
    float a = 0.f;
    for (int e = 0; e < NEXP; e++) {
      float tpe = (float)(tot[e] < CAPD ? tot[e] : CAPD);
      a += tpe * psum_s[e];
    }
    aux_out[0] = 0.01f * (float)NEXP * a / ((float)NTOK * (float)NTOK);
  }
}

// -------- transpose + fp32->fp16 convert: in [E][R][C] -> out [E][C][R] --------
__global__ __launch_bounds__(256) void transpose_cvt_kernel(
    const float* __restrict__ in, _Float16* __restrict__ out, int R, int C) {
  __shared__ float tile[64][65];
  int nC = C >> 6, nR = R >> 6;
  int b = blockIdx.x;
  int e = b / (nR * nC);
  int rem = b % (nR * nC);
  int rt = rem / nC, ct = rem % nC;
  int tid = threadIdx.x;
  int r = tid >> 2, c0 = (tid & 3) * 16;
  const float* ip = in + (size_t)e * R * C + (size_t)(rt * 64 + r) * C + ct * 64 + c0;
#pragma unroll
  for (int j = 0; j < 4; j++) {
    float4 v = *(const float4*)(ip + j * 4);
    tile[r][c0 + j * 4 + 0] = v.x;
    tile[r][c0 + j * 4 + 1] = v.y;
    tile[r][c0 + j * 4 + 2] = v.z;
    tile[r][c0 + j * 4 + 3] = v.w;
  }
  __syncthreads();
  int c = tid >> 2, r0 = (tid & 3) * 16;
  half8_t o0, o1;
#pragma unroll
  for (int j = 0; j < 8; j++) {
    o0[j] = (_Float16)tile[r0 + j][c];
    o1[j] = (_Float16)tile[r0 + 8 + j][c];
  }
  _Float16* op = out + (size_t)e * C * R + (size_t)(ct * 64 + c) * R + rt * 64 + r0;
  *(half8_t*)op = o0;
  *(half8_t*)(op + 8) = o1;
}

// ---------------- gather routed tokens to fp16 [E][CAP][D] ----------------
__global__ __launch_bounds__(256) void gather_kernel(
    const float* __restrict__ x, const int* __restrict__ s2t,
    _Float16* __restrict__ gxb) {
  int slot = blockIdx.x;
  int tok = s2t[slot];
  int tid = threadIdx.x;
  half4_t o;
  if (tok < NTOK) {
    float4 v = *(const float4*)(x + (size_t)tok * DIMD + tid * 4);
    o[0] = (_Float16)v.x; o[1] = (_Float16)v.y;
    o[2] = (_Float16)v.z; o[3] = (_Float16)v.w;
  } else {
    o[0] = o[1] = o[2] = o[3] = (_Float16)0.f;
  }
  *(half4_t*)(gxb + (size_t)slot * DIMD + tid * 4) = o;
}

// ---------------- passthrough for dropped tokens only ----------------
__global__ __launch_bounds__(256) void passthru_kernel(
    const float* __restrict__ x, const int* __restrict__ kept,
    float* __restrict__ out) {
  int tok = blockIdx.x;
  if (kept[tok]) return;
  int tid = threadIdx.x;
  *(float4*)(out + (size_t)tok * DIMD + tid * 4) =
      *(const float4*)(x + (size_t)tok * DIMD + tid * 4);
}

// ---------------- 256x256 deep-pipelined MFMA GEMM core, phase-split ----------------
// C[256x256] += A[256xK] * B^T[256xK], 512 threads = 8 waves (2Mx4N),
// per-wave 128x64 output (8x4 16x16 frags). BK=32.
// Memory machinery identical to the R1-verified version: 4-slot LDS ring
// (128 KB), depth-2 prefetch, counted vmcnt(4) at tile end (tile t+1 landed,
// tile t+2 stays in flight across the barrier), XOR swizzle q^((row>>1)&3)
// applied to the global SOURCE (global_load_lds writes linearly) and to the
// LDS read offset (0 bank conflicts measured in R1).
// m201-style phase interleave: each K-tile = two 16-MFMA phases, each fenced
// {ds_read frags | stage 2 loads -> s_barrier -> lgkmcnt(0)+sched_barrier ->
// setprio(1) -> 16 MFMA -> setprio(0) -> s_barrier}. Race ledger: slot
// (t+2)%4 last read in iter t-2 (>=5 barriers before overwrite); vmcnt at
// tile end: 8 outstanding -> vmcnt(4) lands tile t+1, keeps t+2 in flight.
// Tail: at t=KT-2 pf=false -> wait0 drains tile KT-1 before its reads.
template <int KD>
__device__ __forceinline__ void gemm_core256(const _Float16* __restrict__ A,
                                             const _Float16* __restrict__ B,
                                             _Float16* buf, float4_t acc[8][4]) {
  const int tid = threadIdx.x;  // 0..511
  const _Float16* gp[4];
  int lofs[4];
#pragma unroll
  for (int j = 0; j < 2; ++j) {
    int elem = j * 4096 + tid * 8;   // halfs within a 256x32 matrix
    int row = elem >> 5;
    int q = (elem >> 3) & 3;
    int qs = q ^ ((row >> 1) & 3);   // inverse-swizzled source chunk
    gp[j] = A + (size_t)row * KD + qs * 8;
    gp[2 + j] = B + (size_t)row * KD + qs * 8;
    lofs[j] = elem;             // A region of slot
    lofs[2 + j] = 8192 + elem;  // B region of slot
  }
  const int lane = tid & 63;
  const int wm = ((tid >> 6) >> 2) * 128;  // wave row offset {0,128}
  const int wn = ((tid >> 6) & 3) * 64;    // wave col offset {0,64,128,192}
  const int lr = lane & 15;
  const int ko = ((lane >> 4) ^ ((lr >> 1) & 3)) * 8;
  constexpr int KT = KD / 32;
  // prologue: stage tile 0 -> slot 0, tile 1 -> slot 1
#pragma unroll
  for (int j = 0; j < 4; ++j) async_ld16(buf + lofs[j], gp[j]);
#pragma unroll
  for (int j = 0; j < 4; ++j) {
    async_ld16(buf + 16384 + lofs[j], gp[j] + 32);
    gp[j] += 64;
  }
  wait4_barrier();  // tile 0 landed everywhere; tile 1 still in flight
#pragma unroll 1
  for (int t = 0; t < KT; ++t) {
    const _Float16* As = buf + (t & 3) * 16384;
    const _Float16* Bs = As + 8192;
    _Float16* dst = buf + ((t + 2) & 3) * 16384;
    const bool pf = (t + 2 < KT);
    half8_t bfr[4], a[4];
    // ---------- phase A: B frags + A rows 0..63, MFMA mi=0..3 ----------
#pragma unroll
    for (int i = 0; i < 4; ++i)
      bfr[i] = *(const half8_t*)(Bs + (wn + i * 16 + lr) * 32 + ko);
#pragma unroll
    for (int i = 0; i < 4; ++i)
      a[i] = *(const half8_t*)(As + (wm + i * 16 + lr) * 32 + ko);
    if (pf) {
      async_ld16(dst + lofs[0], gp[0]);
      async_ld16(dst + lofs[1], gp[1]);
    }
    __builtin_amdgcn_s_barrier();
    asm volatile("s_waitcnt lgkmcnt(0)" ::: "memory");
    __builtin_amdgcn_sched_barrier(0);
    __builtin_amdgcn_s_setprio(1);
#pragma unroll
    for (int mi = 0; mi < 4; ++mi)
#pragma unroll
      for (int ni = 0; ni < 4; ++ni)
        acc[mi][ni] =
            __builtin_amdgcn_mfma_f32_16x16x32_f16(a[mi], bfr[ni], acc[mi][ni], 0, 0, 0);
    __builtin_amdgcn_s_setprio(0);
    __builtin_amdgcn_s_barrier();
    // ---------- phase B: A rows 64..127, MFMA mi=4..7 ----------
#pragma unroll
    for (int i = 0; i < 4; ++i)
      a[i] = *(const half8_t*)(As + (wm + 64 + i * 16 + lr) * 32 + ko);
    if (pf) {
      async_ld16(dst + lofs[2], gp[2]);
      async_ld16(dst + lofs[3], gp[3]);
#pragma unroll
      for (int j = 0; j < 4; ++j) gp[j] += 32;
    }
    __builtin_amdgcn_s_barrier();
    asm volatile("s_waitcnt lgkmcnt(0)" ::: "memory");
    __builtin_amdgcn_sched_barrier(0);
    __builtin_amdgcn_s_setprio(1);
#pragma unroll
    for (int mi = 0; mi < 4; ++mi)
#pragma unroll
      for (int ni = 0; ni < 4; ++ni)
        acc[4 + mi][ni] =
            __builtin_amdgcn_mfma_f32_16x16x32_f16(a[mi], bfr[ni], acc[4 + mi][ni], 0, 0, 0);
    __builtin_amdgcn_s_setprio(0);
    if (pf) wait4_barrier(); else wait0_barrier();
  }
}

// ---------------- GEMM1: h = gelu(gx @ W1 + b1), fp16 out ----------------
__global__ __launch_bounds__(512, 2) void gemm1_kernel(
    const _Float16* __restrict__ gxb, const _Float16* __restrict__ w1t,
    const float* __restrict__ b1, _Float16* __restrict__ hb) {
  __shared__ __align__(16) _Float16 buf[65536];  // 128 KB ring
  int blk = blockIdx.x;
  int e = blk / 80;             // 5 M-tiles x 16 N-tiles per expert
  int rem = blk % 80;
  int mb = rem / 16, nb = rem % 16;  // nb fastest: consecutive blocks share A panel (L2)
  const _Float16* A = gxb + (size_t)e * CAPD * DIMD + (size_t)mb * 256 * DIMD;
  const _Float16* B = w1t + (size_t)e * DFFD * DIMD + (size_t)nb * 256 * DIMD;
  float4_t acc[8][4];
#pragma unroll
  for (int mi = 0; mi < 8; ++mi)
#pragma unroll
    for (int ni = 0; ni < 4; ++ni) acc[mi][ni] = (float4_t){0.f, 0.f, 0.f, 0.f};
  gemm_core256<DIMD>(A, B, buf, acc);
  const int tid = threadIdx.x;
  const int lane = tid & 63;
  const int wm = ((tid >> 6) >> 2) * 128, wn = ((tid >> 6) & 3) * 64;
  const int l15 = lane & 15, q4 = (lane >> 4) * 4;
  float bias[4];
#pragma unroll
  for (int ni = 0; ni < 4; ++ni) bias[ni] = b1[e * DFFD + nb * 256 + wn + ni * 16 + l15];
  _Float16* hrow = hb + (size_t)e * CAPD * DFFD + (size_t)(mb * 256) * DFFD + nb * 256;
#pragma unroll
  for (int mi = 0; mi < 8; ++mi)
#pragma unroll
    for (int ni = 0; ni < 4; ++ni)
#pragma unroll
      for (int r = 0; r < 4; ++r) {
        int row = wm + mi * 16 + q4 + r;
        int col = wn + ni * 16 + l15;
        float v = acc[mi][ni][r] + bias[ni];
        hrow[(size_t)row * DFFD + col] = (_Float16)gelu_f(v);
      }
}

// ---------------- GEMM2: final[tok] = (h @ W2 + b2) * gate ----------------
__global__ __launch_bounds__(512, 2) void gemm2_kernel(
    const _Float16* __restrict__ hb, const _Float16* __restrict__ w2t,
    const float* __restrict__ b2, const int* __restrict__ s2t,
    const float* __restrict__ gatef, float* __restrict__ outp) {
  __shared__ __align__(16) _Float16 buf[65536];  // 128 KB ring
  __shared__ int tok_s[256];
  __shared__ float gate_s[256];
  int blk = blockIdx.x;
  int e = blk / 20;             // 5 M-tiles x 4 N-tiles per expert
  int rem = blk % 20;
  int mb = rem / 4, nb = rem % 4;
  int tid = threadIdx.x;
  if (tid < 256) {
    int tok = s2t[e * CAPD + mb * 256 + tid];
    tok_s[tid] = tok;
    gate_s[tid] = (tok < NTOK) ? gatef[tok] : 0.f;
  }
  __syncthreads();  // drains all vmem before the counted-vmcnt core
  const _Float16* A = hb + (size_t)e * CAPD * DFFD + (size_t)mb * 256 * DFFD;
  const _Float16* B = w2t + (size_t)e * DIMD * DFFD + (size_t)nb * 256 * DFFD;
  float4_t acc[8][4];
#pragma unroll
  for (int mi = 0; mi < 8; ++mi)
#pragma unroll
    for (int ni = 0; ni < 4; ++ni) acc[mi][ni] = (float4_t){0.f, 0.f, 0.f, 0.f};
  gemm_core256<DFFD>(A, B, buf, acc);
  const int lane = tid & 63;
  const int wm = ((tid >> 6) >> 2) * 128, wn = ((tid >> 6) & 3) * 64;
  const int l15 = lane & 15, q4 = (lane >> 4) * 4;
  float bias[4];
#pragma unroll
  for (int ni = 0; ni < 4; ++ni) bias[ni] = b2[e * DIMD + nb * 256 + wn + ni * 16 + l15];
#pragma unroll
  for (int mi = 0; mi < 8; ++mi)
#pragma unroll
    for (int r = 0; r < 4; ++r) {
      int row = wm + mi * 16 + q4 + r;
      int tok = tok_s[row];
      float g = gate_s[row];
      if (tok < NTOK) {
#pragma unroll
        for (int ni = 0; ni < 4; ++ni) {
          int col = nb * 256 + wn + ni * 16 + l15;
          outp[(size_t)tok * DIMD + col] = (acc[mi][ni][r] + bias[ni]) * g;
        }
      }
    }
}

extern "C" void kernel_launch(void* const* d_in, const int* in_sizes, int n_in,
                              void* d_out, int out_size, void* d_ws, size_t ws_size,
                              hipStream_t stream) {
  const float* x  = (const float*)d_in[0];
  const float* Wr = (const float*)d_in[1];
  const float* W1 = (const float*)d_in[2];
  const float* b1 = (const float*)d_in[3];
  const float* W2 = (const float*)d_in[4];
  const float* b2 = (const float*)d_in[5];
  float* out = (float*)d_out;

  char* ws = (char*)d_ws;
  float* probs_tok = (float*)ws;                        // 256 KB
  int* eidx   = (int*)(ws + 262144);                    // 32 KB
  float* gate = (float*)(ws + 262144 + 32768);          // 32 KB
  float* gatef = (float*)(ws + 262144 + 65536);         // 32 KB
  int* s2t    = (int*)(ws + 262144 + 98304);            // 40 KB
  int* kept   = (int*)(ws + 262144 + 139264);           // 32 KB
  char* big = ws + 448 * 1024;
  _Float16* gxb = (_Float16*)big;                                   // 20 MB
  _Float16* wt  = (_Float16*)(big + 20971520);                      // 64 MB (W1t, then W2t)
  _Float16* hb  = (_Float16*)(big + 20971520 + 67108864);           // 80 MB

  router_kernel<<<NTOK / 4, 256, 0, stream>>>(x, Wr, eidx, gate, probs_tok);
  scan_kernel<<<1, 256, 0, stream>>>(eidx, gate, probs_tok, gatef, s2t, kept,
                                     out + (size_t)NTOK * DIMD);
  transpose_cvt_kernel<<<NEXP * 16 * 64, 256, 0, stream>>>(W1, wt, DIMD, DFFD);
  gather_kernel<<<NEXP * CAPD, 256, 0, stream>>>(x, s2t, gxb);
  passthru_kernel<<<NTOK, 256, 0, stream>>>(x, kept, out);
  gemm1_kernel<<<NEXP * 5 * 16, 512, 0, stream>>>(gxb, wt, b1, hb);
  transpose_cvt_kernel<<<NEXP * 64 * 16, 256, 0, stream>>>(W2, wt, DFFD, DIMD);
  gemm2_kernel<<<NEXP * 5 * 4, 512, 0, stream>>>(hb, wt, b2, s2t, gatef, out);
}

// Round 4
// 604.895 us; speedup vs baseline: 1.1284x; 1.0665x over previous
//
#include <hip/hip_runtime.h>
#include <stdint.h>

#define NTOK 8192
#define DIMD 1024
#define NEXP 8
#define DFFD 4096
#define CAPD 1280

typedef _Float16 half8_t __attribute__((ext_vector_type(8)));
typedef _Float16 half4_t __attribute__((ext_vector_type(4)));
typedef float float4_t __attribute__((ext_vector_type(4)));

typedef const __attribute__((address_space(1))) uint32_t* gas_ptr_t;
typedef __attribute__((address_space(3))) uint32_t* las_ptr_t;

__device__ __forceinline__ void async_ld16(void* lds, const void* g) {
  __builtin_amdgcn_global_load_lds((gas_ptr_t)g, (las_ptr_t)lds, 16, 0, 0);
}

// Counted-vmcnt barrier: waits only the OLDEST outstanding global_load_lds
// groups, keeps the newest 4 in flight across the workgroup barrier.
__device__ __forceinline__ void wait4_barrier() {
  asm volatile("s_waitcnt vmcnt(4)\n\ts_barrier" ::: "memory");
}
__device__ __forceinline__ void wait0_barrier() {
  asm volatile("s_waitcnt vmcnt(0)\n\ts_barrier" ::: "memory");
}

__device__ __forceinline__ float gelu_f(float v) {
  // tanh-approx gelu (JAX default approximate=True)
  float u = 0.7978845608028654f * (v + 0.044715f * v * v * v);
  float t = 1.f - 2.f / (__expf(2.f * u) + 1.f);
  return 0.5f * v * (1.f + t);
}

// ---------------- router: logits, softmax, gate, argmax ----------------
__global__ __launch_bounds__(256) void router_kernel(
    const float* __restrict__ x, const float* __restrict__ Wr,
    int* __restrict__ eidx, float* __restrict__ gate,
    float* __restrict__ probs_tok) {
  __shared__ float wrt[NEXP * DIMD];  // transposed [e][d]
  int tid = threadIdx.x;
  for (int i = tid; i < NEXP * DIMD; i += 256) {
    int d = i >> 3, e = i & 7;
    wrt[e * DIMD + d] = Wr[i];
  }
  __syncthreads();
  int wave = tid >> 6, lane = tid & 63;
  int tok = blockIdx.x * 4 + wave;
  float acc[NEXP];
#pragma unroll
  for (int e = 0; e < NEXP; e++) acc[e] = 0.f;
  const float* xr = x + (size_t)tok * DIMD;
#pragma unroll
  for (int i = 0; i < DIMD / 64; i++) {
    int d = lane + i * 64;
    float xv = xr[d];
#pragma unroll
    for (int e = 0; e < NEXP; e++) acc[e] += xv * wrt[e * DIMD + d];
  }
#pragma unroll
  for (int off = 32; off >= 1; off >>= 1) {
#pragma unroll
    for (int e = 0; e < NEXP; e++) acc[e] += __shfl_xor(acc[e], off, 64);
  }
  float m = acc[0];
#pragma unroll
  for (int e = 1; e < NEXP; e++) m = fmaxf(m, acc[e]);
  float p[NEXP];
  float s = 0.f;
#pragma unroll
  for (int e = 0; e < NEXP; e++) { p[e] = __expf(acc[e] - m); s += p[e]; }
  float inv = 1.f / s;
  int ei = 0;
  float best = acc[0];
#pragma unroll
  for (int e = 1; e < NEXP; e++) { if (acc[e] > best) { best = acc[e]; ei = e; } }
  if (lane == 0) {
    eidx[tok] = ei;
    gate[tok] = p[ei] * inv;
    float4 pa = make_float4(p[0] * inv, p[1] * inv, p[2] * inv, p[3] * inv);
    float4 pb = make_float4(p[4] * inv, p[5] * inv, p[6] * inv, p[7] * inv);
    float4* pp = (float4*)(probs_tok + (size_t)tok * 8);
    pp[0] = pa;
    pp[1] = pb;
  }
}

// ---------------- ordered capacity scan (single block) ----------------
__global__ __launch_bounds__(256) void scan_kernel(
    const int* __restrict__ eidx, const float* __restrict__ gate,
    const float* __restrict__ probs_tok, float* __restrict__ gatef,
    int* __restrict__ s2t, int* __restrict__ kept_out,
    float* __restrict__ aux_out) {
  __shared__ int cnt[256][NEXP];
  __shared__ float ps[256][NEXP];
  __shared__ int tot[NEXP];
  __shared__ float psum_s[NEXP];
  int tid = threadIdx.x;
  for (int i = tid; i < NEXP * CAPD; i += 256) s2t[i] = NTOK;
  float pa[NEXP];
#pragma unroll
  for (int k = 0; k < NEXP; k++) pa[k] = 0.f;
  for (int b = tid; b < NTOK; b += 256) {
    const float4* p = (const float4*)(probs_tok + (size_t)b * 8);
    float4 v0 = p[0], v1 = p[1];
    pa[0] += v0.x; pa[1] += v0.y; pa[2] += v0.z; pa[3] += v0.w;
    pa[4] += v1.x; pa[5] += v1.y; pa[6] += v1.z; pa[7] += v1.w;
  }
#pragma unroll
  for (int k = 0; k < NEXP; k++) ps[tid][k] = pa[k];
  int c[NEXP];
#pragma unroll
  for (int k = 0; k < NEXP; k++) c[k] = 0;
  int base = tid * 32;
  for (int i = 0; i < 32; i++) {
    int e = eidx[base + i];
#pragma unroll
    for (int k = 0; k < NEXP; k++) c[k] += (e == k);
  }
#pragma unroll
  for (int k = 0; k < NEXP; k++) cnt[tid][k] = c[k];
  __syncthreads();
  if (tid < NEXP) {
    int run = 0;
    for (int j = 0; j < 256; j++) { int v = cnt[j][tid]; cnt[j][tid] = run; run += v; }
    tot[tid] = run;
    float s = 0.f;
    for (int j = 0; j < 256; j++) s += ps[j][tid];
    psum_s[tid] = s;
  }
  __syncthreads();
  int off[NEXP];
#pragma unroll
  for (int k = 0; k < NEXP; k++) off[k] = cnt[tid][k];
  for (int i = 0; i < 32; i++) {
    int t2 = base + i;
    int e = eidx[t2];
    int pos = 0;
#pragma unroll
    for (int k = 0; k < NEXP; k++) pos += (e == k) ? off[k] : 0;
    bool kept = pos < CAPD;
    gatef[t2] = kept ? gate[t2] : 0.f;
    kept_out[t2] = kept ? 1 : 0;
    if (kept) s2t[e * CAPD + pos] = t2;
#pragma unroll
    for (int k = 0; k < NEXP; k++) off[k] += (e == k);
  }
  if (tid == 0) {
    float a = 0.f;
    for (int e = 0; e < NEXP; e++) {
      float tpe = (float)(tot[e] < CAPD ? tot[e] : CAPD);
      a += tpe * psum_s[e];
    }
    aux_out[0] = 0.01f * (float)NEXP * a / ((float)NTOK * (float)NTOK);
  }
}

// -------- transpose + fp32->fp16 convert: in [E][R][C] -> out [E][C][R] --------
__global__ __launch_bounds__(256) void transpose_cvt_kernel(
    const float* __restrict__ in, _Float16* __restrict__ out, int R, int C) {
  __shared__ float tile[64][65];
  int nC = C >> 6, nR = R >> 6;
  int b = blockIdx.x;
  int e = b / (nR * nC);
  int rem = b % (nR * nC);
  int rt = rem / nC, ct = rem % nC;
  int tid = threadIdx.x;
  int r = tid >> 2, c0 = (tid & 3) * 16;
  const float* ip = in + (size_t)e * R * C + (size_t)(rt * 64 + r) * C + ct * 64 + c0;
#pragma unroll
  for (int j = 0; j < 4; j++) {
    float4 v = *(const float4*)(ip + j * 4);
    tile[r][c0 + j * 4 + 0] = v.x;
    tile[r][c0 + j * 4 + 1] = v.y;
    tile[r][c0 + j * 4 + 2] = v.z;
    tile[r][c0 + j * 4 + 3] = v.w;
  }
  __syncthreads();
  int c = tid >> 2, r0 = (tid & 3) * 16;
  half8_t o0, o1;
#pragma unroll
  for (int j = 0; j < 8; j++) {
    o0[j] = (_Float16)tile[r0 + j][c];
    o1[j] = (_Float16)tile[r0 + 8 + j][c];
  }
  _Float16* op = out + (size_t)e * C * R + (size_t)(ct * 64 + c) * R + rt * 64 + r0;
  *(half8_t*)op = o0;
  *(half8_t*)(op + 8) = o1;
}

// ---------------- gather routed tokens to fp16 [E][CAP][D] ----------------
__global__ __launch_bounds__(256) void gather_kernel(
    const float* __restrict__ x, const int* __restrict__ s2t,
    _Float16* __restrict__ gxb) {
  int slot = blockIdx.x;
  int tok = s2t[slot];
  int tid = threadIdx.x;
  half4_t o;
  if (tok < NTOK) {
    float4 v = *(const float4*)(x + (size_t)tok * DIMD + tid * 4);
    o[0] = (_Float16)v.x; o[1] = (_Float16)v.y;
    o[2] = (_Float16)v.z; o[3] = (_Float16)v.w;
  } else {
    o[0] = o[1] = o[2] = o[3] = (_Float16)0.f;
  }
  *(half4_t*)(gxb + (size_t)slot * DIMD + tid * 4) = o;
}

// ---------------- passthrough for dropped tokens only ----------------
__global__ __launch_bounds__(256) void passthru_kernel(
    const float* __restrict__ x, const int* __restrict__ kept,
    float* __restrict__ out) {
  int tok = blockIdx.x;
  if (kept[tok]) return;
  int tid = threadIdx.x;
  *(float4*)(out + (size_t)tok * DIMD + tid * 4) =
      *(const float4*)(x + (size_t)tok * DIMD + tid * 4);
}

// -------- 128x128 phase-fenced MFMA GEMM core, 3-slot ring, depth-2 --------
// C[128x128] += A[128xK] * B^T[128xK]. 256 threads = 4 waves (2Mx2N), each
// wave 64x64 (4x4 16x16 frags), 16 MFMA per K-tile. BK=32.
// LDS: 3-slot ring, slot = A[128][32]+B[128][32] f16 = 16 KB -> 48 KB total
// -> 3 blocks/CU (with tok tables ~49KB, still 3/CU). Cross-block overlap
// (m114) hides per-phase ds_read latency + barrier joins.
// Depth-2 prefetch in a 3-ring is safe: slot (t+2)%3 == (t-1)%3, whose last
// readers (iter t-1) passed lgkmcnt(0) before the end-of-iter-(t-1) barrier,
// which precedes iter-t's stage issues. vmcnt ledger: 4 loads/tile; at tile
// end 8 outstanding -> vmcnt(4) lands tile t+1, keeps t+2 in flight (never
// drains to 0 in steady state). Tail: pf=false -> wait0 before last reads.
// Phase fence per iter: {8 ds_reads | 4 stage -> s_barrier -> lgkmcnt(0)+
// sched_barrier -> setprio(1) -> 16 MFMA -> setprio(0) -> counted barrier}.
// XOR swizzle q^((row>>1)&3) on the global SOURCE (global_load_lds writes
// linearly) and on the LDS read offset ko (0 bank conflicts, R1-verified).
template <int KD>
__device__ __forceinline__ void gemm_core128(const _Float16* __restrict__ A,
                                             const _Float16* __restrict__ B,
                                             _Float16* buf, float4_t acc[4][4]) {
  const int tid = threadIdx.x;  // 0..255
  const _Float16* gp[4];
  int lofs[4];
#pragma unroll
  for (int j = 0; j < 2; ++j) {
    int elem = j * 2048 + tid * 8;   // halfs within a 128x32 matrix
    int row = elem >> 5;
    int q = (elem >> 3) & 3;
    int qs = q ^ ((row >> 1) & 3);   // inverse-swizzled source chunk
    gp[j] = A + (size_t)row * KD + qs * 8;
    gp[2 + j] = B + (size_t)row * KD + qs * 8;
    lofs[j] = elem;             // A region of slot
    lofs[2 + j] = 4096 + elem;  // B region of slot
  }
  const int lane = tid & 63;
  const int wid = tid >> 6;
  const int wm = (wid >> 1) * 64, wn = (wid & 1) * 64;
  const int lr = lane & 15;
  const int ko = ((lane >> 4) ^ ((lr >> 1) & 3)) * 8;
  constexpr int KT = KD / 32;
  // prologue: stage tile 0 -> slot 0, tile 1 -> slot 1
#pragma unroll
  for (int j = 0; j < 4; ++j) async_ld16(buf + lofs[j], gp[j]);
#pragma unroll
  for (int j = 0; j < 4; ++j) {
    async_ld16(buf + 8192 + lofs[j], gp[j] + 32);
    gp[j] += 64;
  }
  wait4_barrier();  // tile 0 landed everywhere; tile 1 still in flight
  int sc = 0, sp = 2;  // current slot, prefetch slot = (t+2)%3
#pragma unroll 1
  for (int t = 0; t < KT; ++t) {
    const _Float16* As = buf + sc * 8192;
    const _Float16* Bs = As + 4096;
    const bool pf = (t + 2 < KT);
    half8_t a[4], b[4];
#pragma unroll
    for (int i = 0; i < 4; ++i)
      b[i] = *(const half8_t*)(Bs + (wn + i * 16 + lr) * 32 + ko);
#pragma unroll
    for (int i = 0; i < 4; ++i)
      a[i] = *(const half8_t*)(As + (wm + i * 16 + lr) * 32 + ko);
    if (pf) {
      _Float16* dst = buf + sp * 8192;
#pragma unroll
      for (int j = 0; j < 4; ++j) { async_ld16(dst + lofs[j], gp[j]); gp[j] += 32; }
    }
    __builtin_amdgcn_s_barrier();
    asm volatile("s_waitcnt lgkmcnt(0)" ::: "memory");
    __builtin_amdgcn_sched_barrier(0);
    __builtin_amdgcn_s_setprio(1);
#pragma unroll
    for (int mi = 0; mi < 4; ++mi)
#pragma unroll
      for (int ni = 0; ni < 4; ++ni)
        acc[mi][ni] =
            __builtin_amdgcn_mfma_f32_16x16x32_f16(a[mi], b[ni], acc[mi][ni], 0, 0, 0);
    __builtin_amdgcn_s_setprio(0);
    if (pf) wait4_barrier(); else wait0_barrier();
    sc = (sc == 2) ? 0 : sc + 1;
    sp = (sp == 2) ? 0 : sp + 1;
  }
}

// ---------------- GEMM1: h = gelu(gx @ W1 + b1), fp16 out ----------------
__global__ __launch_bounds__(256, 3) void gemm1_kernel(
    const _Float16* __restrict__ gxb, const _Float16* __restrict__ w1t,
    const float* __restrict__ b1, _Float16* __restrict__ hb) {
  __shared__ __align__(16) _Float16 buf[24576];  // 48 KB 3-slot ring
  // XCD-aware bijective swizzle (grid = 2560 = 8*320; one expert per XCD)
  int nwg = gridDim.x;
  int bx = blockIdx.x;
  int blk = (bx & 7) * (nwg >> 3) + (bx >> 3);
  int e = blk / 320;            // 10 M-tiles x 32 N-tiles per expert
  int rem = blk % 320;
  int mb = rem / 32, nb = rem % 32;  // nb fastest: consecutive blocks share A panel
  const _Float16* A = gxb + (size_t)e * CAPD * DIMD + (size_t)mb * 128 * DIMD;
  const _Float16* B = w1t + (size_t)e * DFFD * DIMD + (size_t)nb * 128 * DIMD;
  float4_t acc[4][4];
#pragma unroll
  for (int mi = 0; mi < 4; ++mi)
#pragma unroll
    for (int ni = 0; ni < 4; ++ni) acc[mi][ni] = (float4_t){0.f, 0.f, 0.f, 0.f};
  gemm_core128<DIMD>(A, B, buf, acc);
  const int tid = threadIdx.x;
  const int lane = tid & 63;
  const int wid = tid >> 6;
  const int wm = (wid >> 1) * 64, wn = (wid & 1) * 64;
  const int l15 = lane & 15, q4 = (lane >> 4) * 4;
  float bias[4];
#pragma unroll
  for (int ni = 0; ni < 4; ++ni) bias[ni] = b1[e * DFFD + nb * 128 + wn + ni * 16 + l15];
  _Float16* hrow = hb + (size_t)e * CAPD * DFFD + (size_t)(mb * 128) * DFFD + nb * 128;
#pragma unroll
  for (int mi = 0; mi < 4; ++mi)
#pragma unroll
    for (int ni = 0; ni < 4; ++ni)
#pragma unroll
      for (int r = 0; r < 4; ++r) {
        int row = wm + mi * 16 + q4 + r;
        int col = wn + ni * 16 + l15;
        float v = acc[mi][ni][r] + bias[ni];
        hrow[(size_t)row * DFFD + col] = (_Float16)gelu_f(v);
      }
}

// ---------------- GEMM2: final[tok] = (h @ W2 + b2) * gate ----------------
__global__ __launch_bounds__(256, 3) void gemm2_kernel(
    const _Float16* __restrict__ hb, const _Float16* __restrict__ w2t,
    const float* __restrict__ b2, const int* __restrict__ s2t,
    const float* __restrict__ gatef, float* __restrict__ outp) {
  __shared__ __align__(16) _Float16 buf[24576];  // 48 KB 3-slot ring
  __shared__ int tok_s[128];
  __shared__ float gate_s[128];
  // XCD-aware bijective swizzle (grid = 640 = 8*80; one expert per XCD)
  int nwg = gridDim.x;
  int bx = blockIdx.x;
  int blk = (bx & 7) * (nwg >> 3) + (bx >> 3);
  int e = blk / 80;             // 10 M-tiles x 8 N-tiles per expert
  int rem = blk % 80;
  int mb = rem / 8, nb = rem % 8;
  int tid = threadIdx.x;
  if (tid < 128) {
    int tok = s2t[e * CAPD + mb * 128 + tid];
    tok_s[tid] = tok;
    gate_s[tid] = (tok < NTOK) ? gatef[tok] : 0.f;
  }
  __syncthreads();  // drains all vmem before the counted-vmcnt core
  const _Float16* A = hb + (size_t)e * CAPD * DFFD + (size_t)mb * 128 * DFFD;
  const _Float16* B = w2t + (size_t)e * DIMD * DFFD + (size_t)nb * 128 * DFFD;
  float4_t acc[4][4];
#pragma unroll
  for (int mi = 0; mi < 4; ++mi)
#pragma unroll
    for (int ni = 0; ni < 4; ++ni) acc[mi][ni] = (float4_t){0.f, 0.f, 0.f, 0.f};
  gemm_core128<DFFD>(A, B, buf, acc);
  const int lane = tid & 63;
  const int wid = tid >> 6;
  const int wm = (wid >> 1) * 64, wn = (wid & 1) * 64;
  const int l15 = lane & 15, q4 = (lane >> 4) * 4;
  float bias[4];
#pragma unroll
  for (int ni = 0; ni < 4; ++ni) bias[ni] = b2[e * DIMD + nb * 128 + wn + ni * 16 + l15];
#pragma unroll
  for (int mi = 0; mi < 4; ++mi)
#pragma unroll
    for (int r = 0; r < 4; ++r) {
      int row = wm + mi * 16 + q4 + r;
      int tok = tok_s[row];
      float g = gate_s[row];
      if (tok < NTOK) {
#pragma unroll
        for (int ni = 0; ni < 4; ++ni) {
          int col = nb * 128 + wn + ni * 16 + l15;
          outp[(size_t)tok * DIMD + col] = (acc[mi][ni][r] + bias[ni]) * g;
        }
      }
    }
}

extern "C" void kernel_launch(void* const* d_in, const int* in_sizes, int n_in,
                              void* d_out, int out_size, void* d_ws, size_t ws_size,
                              hipStream_t stream) {
  const float* x  = (const float*)d_in[0];
  const float* Wr = (const float*)d_in[1];
  const float* W1 = (const float*)d_in[2];
  const float* b1 = (const float*)d_in[3];
  const float* W2 = (const float*)d_in[4];
  const float* b2 = (const float*)d_in[5];
  float* out = (float*)d_out;

  char* ws = (char*)d_ws;
  float* probs_tok = (float*)ws;                        // 256 KB
  int* eidx   = (int*)(ws + 262144);                    // 32 KB
  float* gate = (float*)(ws + 262144 + 32768);          // 32 KB
  float* gatef = (float*)(ws + 262144 + 65536);         // 32 KB
  int* s2t    = (int*)(ws + 262144 + 98304);            // 40 KB
  int* kept   = (int*)(ws + 262144 + 139264);           // 32 KB
  char* big = ws + 448 * 1024;
  _Float16* gxb = (_Float16*)big;                                   // 20 MB
  _Float16* wt  = (_Float16*)(big + 20971520);                      // 64 MB (W1t, then W2t)
  _Float16* hb  = (_Float16*)(big + 20971520 + 67108864);           // 80 MB

  router_kernel<<<NTOK / 4, 256, 0, stream>>>(x, Wr, eidx, gate, probs_tok);
  scan_kernel<<<1, 256, 0, stream>>>(eidx, gate, probs_tok, gatef, s2t, kept,
                                     out + (size_t)NTOK * DIMD);
  transpose_cvt_kernel<<<NEXP * 16 * 64, 256, 0, stream>>>(W1, wt, DIMD, DFFD);
  gather_kernel<<<NEXP * CAPD, 256, 0, stream>>>(x, s2t, gxb);
  passthru_kernel<<<NTOK, 256, 0, stream>>>(x, kept, out);
  gemm1_kernel<<<NEXP * 10 * 32, 256, 0, stream>>>(gxb, wt, b1, hb);
  transpose_cvt_kernel<<<NEXP * 64 * 16, 256, 0, stream>>>(W2, wt, DFFD, DIMD);
  gemm2_kernel<<<NEXP * 10 * 8, 256, 0, stream>>>(hb, wt, b2, s2t, gatef, out);
}

// Round 5
// 598.598 us; speedup vs baseline: 1.1403x; 1.0105x over previous
//
#include <hip/hip_runtime.h>
#include <stdint.h>

#define NTOK 8192
#define DIMD 1024
#define NEXP 8
#define DFFD 4096
#define CAPD 1280

typedef _Float16 half8_t __attribute__((ext_vector_type(8)));
typedef _Float16 half4_t __attribute__((ext_vector_type(4)));
typedef float float4_t __attribute__((ext_vector_type(4)));

typedef const __attribute__((address_space(1))) uint32_t* gas_ptr_t;
typedef __attribute__((address_space(3))) uint32_t* las_ptr_t;

__device__ __forceinline__ void async_ld16(void* lds, const void* g) {
  __builtin_amdgcn_global_load_lds((gas_ptr_t)g, (las_ptr_t)lds, 16, 0, 0);
}

// Counted-vmcnt barrier: waits only the OLDEST outstanding global_load_lds
// groups, keeps the newest 4 in flight across the workgroup barrier.
__device__ __forceinline__ void wait4_barrier() {
  asm volatile("s_waitcnt vmcnt(4)\n\ts_barrier" ::: "memory");
}
__device__ __forceinline__ void wait0_barrier() {
  asm volatile("s_waitcnt vmcnt(0)\n\ts_barrier" ::: "memory");
}

__device__ __forceinline__ float gelu_f(float v) {
  // tanh-approx gelu (JAX default approximate=True)
  float u = 0.7978845608028654f * (v + 0.044715f * v * v * v);
  float t = 1.f - 2.f / (__expf(2.f * u) + 1.f);
  return 0.5f * v * (1.f + t);
}

// ---------------- transpose body: in [E][R][C] fp32 -> out [E][C][R] fp16 ----
__device__ __forceinline__ void transpose_body(
    const float* __restrict__ in, _Float16* __restrict__ out, int R, int C,
    int b, char* smem) {
  float (*tile)[65] = (float (*)[65])smem;
  int nC = C >> 6, nR = R >> 6;
  int e = b / (nR * nC);
  int rem = b % (nR * nC);
  int rt = rem / nC, ct = rem % nC;
  int tid = threadIdx.x;
  int r = tid >> 2, c0 = (tid & 3) * 16;
  const float* ip = in + (size_t)e * R * C + (size_t)(rt * 64 + r) * C + ct * 64 + c0;
#pragma unroll
  for (int j = 0; j < 4; j++) {
    float4 v = *(const float4*)(ip + j * 4);
    tile[r][c0 + j * 4 + 0] = v.x;
    tile[r][c0 + j * 4 + 1] = v.y;
    tile[r][c0 + j * 4 + 2] = v.z;
    tile[r][c0 + j * 4 + 3] = v.w;
  }
  __syncthreads();
  int c = tid >> 2, r0 = (tid & 3) * 16;
  half8_t o0, o1;
#pragma unroll
  for (int j = 0; j < 8; j++) {
    o0[j] = (_Float16)tile[r0 + j][c];
    o1[j] = (_Float16)tile[r0 + 8 + j][c];
  }
  _Float16* op = out + (size_t)e * C * R + (size_t)(ct * 64 + c) * R + rt * 64 + r0;
  *(half8_t*)op = o0;
  *(half8_t*)(op + 8) = o1;
}

// ---------------- router body: logits, softmax, gate, argmax ----------------
__device__ __forceinline__ void router_body(
    const float* __restrict__ x, const float* __restrict__ Wr,
    int* __restrict__ eidx, float* __restrict__ gate,
    float* __restrict__ probs_tok, int bid, char* smem) {
  float* wrt = (float*)smem;  // transposed [e][d], 32 KB
  int tid = threadIdx.x;
  for (int i = tid; i < NEXP * DIMD; i += 256) {
    int d = i >> 3, e = i & 7;
    wrt[e * DIMD + d] = Wr[i];
  }
  __syncthreads();
  int wave = tid >> 6, lane = tid & 63;
  int tok = bid * 4 + wave;
  float acc[NEXP];
#pragma unroll
  for (int e = 0; e < NEXP; e++) acc[e] = 0.f;
  const float* xr = x + (size_t)tok * DIMD;
#pragma unroll
  for (int i = 0; i < DIMD / 64; i++) {
    int d = lane + i * 64;
    float xv = xr[d];
#pragma unroll
    for (int e = 0; e < NEXP; e++) acc[e] += xv * wrt[e * DIMD + d];
  }
#pragma unroll
  for (int off = 32; off >= 1; off >>= 1) {
#pragma unroll
    for (int e = 0; e < NEXP; e++) acc[e] += __shfl_xor(acc[e], off, 64);
  }
  float m = acc[0];
#pragma unroll
  for (int e = 1; e < NEXP; e++) m = fmaxf(m, acc[e]);
  float p[NEXP];
  float s = 0.f;
#pragma unroll
  for (int e = 0; e < NEXP; e++) { p[e] = __expf(acc[e] - m); s += p[e]; }
  float inv = 1.f / s;
  int ei = 0;
  float best = acc[0];
#pragma unroll
  for (int e = 1; e < NEXP; e++) { if (acc[e] > best) { best = acc[e]; ei = e; } }
  if (lane == 0) {
    eidx[tok] = ei;
    gate[tok] = p[ei] * inv;
    float4 pa = make_float4(p[0] * inv, p[1] * inv, p[2] * inv, p[3] * inv);
    float4 pb = make_float4(p[4] * inv, p[5] * inv, p[6] * inv, p[7] * inv);
    float4* pp = (float4*)(probs_tok + (size_t)tok * 8);
    pp[0] = pa;
    pp[1] = pb;
  }
}

// -------- fused: W1 transpose (blocks 0..8191) + router (blocks 8192..10239) --
__global__ __launch_bounds__(256) void pre_kernel(
    const float* __restrict__ x, const float* __restrict__ Wr,
    const float* __restrict__ W1, _Float16* __restrict__ w1t,
    int* __restrict__ eidx, float* __restrict__ gate,
    float* __restrict__ probs_tok) {
  __shared__ __align__(16) char smem[NEXP * DIMD * 4];  // 32 KB (max of roles)
  int b = blockIdx.x;
  if (b < NEXP * 16 * 64) {
    transpose_body(W1, w1t, DIMD, DFFD, b, smem);
  } else {
    router_body(x, Wr, eidx, gate, probs_tok, b - NEXP * 16 * 64, smem);
  }
}

// ---------------- ordered capacity scan (single block) ----------------
__global__ __launch_bounds__(256) void scan_kernel(
    const int* __restrict__ eidx, const float* __restrict__ gate,
    const float* __restrict__ probs_tok, float* __restrict__ gatef,
    int* __restrict__ s2t, int* __restrict__ kept_out,
    float* __restrict__ aux_out) {
  __shared__ int cnt[256][NEXP];
  __shared__ float ps[256][NEXP];
  __shared__ int tot[NEXP];
  __shared__ float psum_s[NEXP];
  int tid = threadIdx.x;
  for (int i = tid; i < NEXP * CAPD; i += 256) s2t[i] = NTOK;
  float pa[NEXP];
#pragma unroll
  for (int k = 0; k < NEXP; k++) pa[k] = 0.f;
  for (int b = tid; b < NTOK; b += 256) {
    const float4* p = (const float4*)(probs_tok + (size_t)b * 8);
    float4 v0 = p[0], v1 = p[1];
    pa[0] += v0.x; pa[1] += v0.y; pa[2] += v0.z; pa[3] += v0.w;
    pa[4] += v1.x; pa[5] += v1.y; pa[6] += v1.z; pa[7] += v1.w;
  }
#pragma unroll
  for (int k = 0; k < NEXP; k++) ps[tid][k] = pa[k];
  int c[NEXP];
#pragma unroll
  for (int k = 0; k < NEXP; k++) c[k] = 0;
  int base = tid * 32;
  for (int i = 0; i < 32; i++) {
    int e = eidx[base + i];
#pragma unroll
    for (int k = 0; k < NEXP; k++) c[k] += (e == k);
  }
#pragma unroll
  for (int k = 0; k < NEXP; k++) cnt[tid][k] = c[k];
  __syncthreads();
  if (tid < NEXP) {
    int run = 0;
    for (int j = 0; j < 256; j++) { int v = cnt[j][tid]; cnt[j][tid] = run; run += v; }
    tot[tid] = run;
    float s = 0.f;
    for (int j = 0; j < 256; j++) s += ps[j][tid];
    psum_s[tid] = s;
  }
  __syncthreads();
  int off[NEXP];
#pragma unroll
  for (int k = 0; k < NEXP; k++) off[k] = cnt[tid][k];
  for (int i = 0; i < 32; i++) {
    int t2 = base + i;
    int e = eidx[t2];
    int pos = 0;
#pragma unroll
    for (int k = 0; k < NEXP; k++) pos += (e == k) ? off[k] : 0;
    bool kept = pos < CAPD;
    gatef[t2] = kept ? gate[t2] : 0.f;
    kept_out[t2] = kept ? 1 : 0;
    if (kept) s2t[e * CAPD + pos] = t2;
#pragma unroll
    for (int k = 0; k < NEXP; k++) off[k] += (e == k);
  }
  if (tid == 0) {
    float a = 0.f;
    for (int e = 0; e < NEXP; e++) {
      float tpe = (float)(tot[e] < CAPD ? tot[e] : CAPD);
      a += tpe * psum_s[e];
    }
    aux_out[0] = 0.01f * (float)NEXP * a / ((float)NTOK * (float)NTOK);
  }
}

// ---- plain transpose kernel (used for W2 after gemm1 frees wt) ----
__global__ __launch_bounds__(256) void transpose_cvt_kernel(
    const float* __restrict__ in, _Float16* __restrict__ out, int R, int C) {
  __shared__ __align__(16) char smem[64 * 65 * 4];
  transpose_body(in, out, R, C, blockIdx.x, smem);
}

// -------- fused: gather (blocks 0..10239) + passthrough (10240..18431) --------
__global__ __launch_bounds__(256) void gp_kernel(
    const float* __restrict__ x, const int* __restrict__ s2t,
    const int* __restrict__ kept, _Float16* __restrict__ gxb,
    float* __restrict__ out) {
  int b = blockIdx.x;
  int tid = threadIdx.x;
  if (b < NEXP * CAPD) {
    int tok = s2t[b];
    half4_t o;
    if (tok < NTOK) {
      float4 v = *(const float4*)(x + (size_t)tok * DIMD + tid * 4);
      o[0] = (_Float16)v.x; o[1] = (_Float16)v.y;
      o[2] = (_Float16)v.z; o[3] = (_Float16)v.w;
    } else {
      o[0] = o[1] = o[2] = o[3] = (_Float16)0.f;
    }
    *(half4_t*)(gxb + (size_t)b * DIMD + tid * 4) = o;
  } else {
    int tok = b - NEXP * CAPD;
    if (kept[tok]) return;
    *(float4*)(out + (size_t)tok * DIMD + tid * 4) =
        *(const float4*)(x + (size_t)tok * DIMD + tid * 4);
  }
}

// -------- 128x128 phase-fenced MFMA GEMM core, 3-slot ring, depth-2 --------
// (R4-verified; unchanged.) C[128x128] += A[128xK] * B^T[128xK]. 256 threads
// = 4 waves (2Mx2N), wave 64x64 (4x4 16x16 frags), BK=32. 3-slot LDS ring
// (48 KB -> 3 blocks/CU). Depth-2 prefetch; vmcnt(4) at tile end lands tile
// t+1, keeps t+2 in flight. Phase fence: {8 ds_reads | 4 stage -> s_barrier
// -> lgkmcnt(0)+sched_barrier -> setprio(1) -> 16 MFMA -> setprio(0) ->
// counted barrier}. XOR swizzle q^((row>>1)&3) on global source + LDS reads.
template <int KD>
__device__ __forceinline__ void gemm_core128(const _Float16* __restrict__ A,
                                             const _Float16* __restrict__ B,
                                             _Float16* buf, float4_t acc[4][4]) {
  const int tid = threadIdx.x;  // 0..255
  const _Float16* gp[4];
  int lofs[4];
#pragma unroll
  for (int j = 0; j < 2; ++j) {
    int elem = j * 2048 + tid * 8;   // halfs within a 128x32 matrix
    int row = elem >> 5;
    int q = (elem >> 3) & 3;
    int qs = q ^ ((row >> 1) & 3);   // inverse-swizzled source chunk
    gp[j] = A + (size_t)row * KD + qs * 8;
    gp[2 + j] = B + (size_t)row * KD + qs * 8;
    lofs[j] = elem;             // A region of slot
    lofs[2 + j] = 4096 + elem;  // B region of slot
  }
  const int lane = tid & 63;
  const int wid = tid >> 6;
  const int wm = (wid >> 1) * 64, wn = (wid & 1) * 64;
  const int lr = lane & 15;
  const int ko = ((lane >> 4) ^ ((lr >> 1) & 3)) * 8;
  constexpr int KT = KD / 32;
  // prologue: stage tile 0 -> slot 0, tile 1 -> slot 1
#pragma unroll
  for (int j = 0; j < 4; ++j) async_ld16(buf + lofs[j], gp[j]);
#pragma unroll
  for (int j = 0; j < 4; ++j) {
    async_ld16(buf + 8192 + lofs[j], gp[j] + 32);
    gp[j] += 64;
  }
  wait4_barrier();  // tile 0 landed everywhere; tile 1 still in flight
  int sc = 0, sp = 2;  // current slot, prefetch slot = (t+2)%3
#pragma unroll 1
  for (int t = 0; t < KT; ++t) {
    const _Float16* As = buf + sc * 8192;
    const _Float16* Bs = As + 4096;
    const bool pf = (t + 2 < KT);
    half8_t a[4], b[4];
#pragma unroll
    for (int i = 0; i < 4; ++i)
      b[i] = *(const half8_t*)(Bs + (wn + i * 16 + lr) * 32 + ko);
#pragma unroll
    for (int i = 0; i < 4; ++i)
      a[i] = *(const half8_t*)(As + (wm + i * 16 + lr) * 32 + ko);
    if (pf) {
      _Float16* dst = buf + sp * 8192;
#pragma unroll
      for (int j = 0; j < 4; ++j) { async_ld16(dst + lofs[j], gp[j]); gp[j] += 32; }
    }
    __builtin_amdgcn_s_barrier();
    asm volatile("s_waitcnt lgkmcnt(0)" ::: "memory");
    __builtin_amdgcn_sched_barrier(0);
    __builtin_amdgcn_s_setprio(1);
#pragma unroll
    for (int mi = 0; mi < 4; ++mi)
#pragma unroll
      for (int ni = 0; ni < 4; ++ni)
        acc[mi][ni] =
            __builtin_amdgcn_mfma_f32_16x16x32_f16(a[mi], b[ni], acc[mi][ni], 0, 0, 0);
    __builtin_amdgcn_s_setprio(0);
    if (pf) wait4_barrier(); else wait0_barrier();
    sc = (sc == 2) ? 0 : sc + 1;
    sp = (sp == 2) ? 0 : sp + 1;
  }
}

// ---------------- GEMM1: h = gelu(gx @ W1 + b1), fp16 out ----------------
__global__ __launch_bounds__(256, 3) void gemm1_kernel(
    const _Float16* __restrict__ gxb, const _Float16* __restrict__ w1t,
    const float* __restrict__ b1, _Float16* __restrict__ hb) {
  __shared__ __align__(16) _Float16 buf[24576];  // 48 KB 3-slot ring
  // XCD-aware bijective swizzle (grid = 2560 = 8*320; one expert per XCD)
  int nwg = gridDim.x;
  int bx = blockIdx.x;
  int blk = (bx & 7) * (nwg >> 3) + (bx >> 3);
  int e = blk / 320;
  int rem = blk % 320;
  // mb fastest: concurrent blocks share nb's B-panel (fetched once) while
  // the expert's whole A (2.5 MB) stays resident in the 4 MB XCD-L2.
  int mb = rem % 10, nb = rem / 10;
  const _Float16* A = gxb + (size_t)e * CAPD * DIMD + (size_t)mb * 128 * DIMD;
  const _Float16* B = w1t + (size_t)e * DFFD * DIMD + (size_t)nb * 128 * DIMD;
  float4_t acc[4][4];
#pragma unroll
  for (int mi = 0; mi < 4; ++mi)
#pragma unroll
    for (int ni = 0; ni < 4; ++ni) acc[mi][ni] = (float4_t){0.f, 0.f, 0.f, 0.f};
  gemm_core128<DIMD>(A, B, buf, acc);
  const int tid = threadIdx.x;
  const int lane = tid & 63;
  const int wid = tid >> 6;
  const int wm = (wid >> 1) * 64, wn = (wid & 1) * 64;
  const int l15 = lane & 15, q4 = (lane >> 4) * 4;
  float bias[4];
#pragma unroll
  for (int ni = 0; ni < 4; ++ni) bias[ni] = b1[e * DFFD + nb * 128 + wn + ni * 16 + l15];
  _Float16* hrow = hb + (size_t)e * CAPD * DFFD + (size_t)(mb * 128) * DFFD + nb * 128;
#pragma unroll
  for (int mi = 0; mi < 4; ++mi)
#pragma unroll
    for (int ni = 0; ni < 4; ++ni)
#pragma unroll
      for (int r = 0; r < 4; ++r) {
        int row = wm + mi * 16 + q4 + r;
        int col = wn + ni * 16 + l15;
        float v = acc[mi][ni][r] + bias[ni];
        hrow[(size_t)row * DFFD + col] = (_Float16)gelu_f(v);
      }
}

// ---------------- GEMM2: final[tok] = (h @ W2 + b2) * gate ----------------
__global__ __launch_bounds__(256, 3) void gemm2_kernel(
    const _Float16* __restrict__ hb, const _Float16* __restrict__ w2t,
    const float* __restrict__ b2, const int* __restrict__ s2t,
    const float* __restrict__ gatef, float* __restrict__ outp) {
  __shared__ __align__(16) _Float16 buf[24576];  // 48 KB 3-slot ring
  __shared__ int tok_s[128];
  __shared__ float gate_s[128];
  // XCD-aware bijective swizzle (grid = 640 = 8*80; one expert per XCD)
  int nwg = gridDim.x;
  int bx = blockIdx.x;
  int blk = (bx & 7) * (nwg >> 3) + (bx >> 3);
  int e = blk / 80;
  int rem = blk % 80;
  int mb = rem / 8, nb = rem % 8;
  int tid = threadIdx.x;
  if (tid < 128) {
    int tok = s2t[e * CAPD + mb * 128 + tid];
    tok_s[tid] = tok;
    gate_s[tid] = (tok < NTOK) ? gatef[tok] : 0.f;
  }
  __syncthreads();  // drains all vmem before the counted-vmcnt core
  const _Float16* A = hb + (size_t)e * CAPD * DFFD + (size_t)mb * 128 * DFFD;
  const _Float16* B = w2t + (size_t)e * DIMD * DFFD + (size_t)nb * 128 * DFFD;
  float4_t acc[4][4];
#pragma unroll
  for (int mi = 0; mi < 4; ++mi)
#pragma unroll
    for (int ni = 0; ni < 4; ++ni) acc[mi][ni] = (float4_t){0.f, 0.f, 0.f, 0.f};
  gemm_core128<DFFD>(A, B, buf, acc);
  const int lane = tid & 63;
  const int wid = tid >> 6;
  const int wm = (wid >> 1) * 64, wn = (wid & 1) * 64;
  const int l15 = lane & 15, q4 = (lane >> 4) * 4;
  float bias[4];
#pragma unroll
  for (int ni = 0; ni < 4; ++ni) bias[ni] = b2[e * DIMD + nb * 128 + wn + ni * 16 + l15];
#pragma unroll
  for (int mi = 0; mi < 4; ++mi)
#pragma unroll
    for (int r = 0; r < 4; ++r) {
      int row = wm + mi * 16 + q4 + r;
      int tok = tok_s[row];
      float g = gate_s[row];
      if (tok < NTOK) {
#pragma unroll
        for (int ni = 0; ni < 4; ++ni) {
          int col = nb * 128 + wn + ni * 16 + l15;
          outp[(size_t)tok * DIMD + col] = (acc[mi][ni][r] + bias[ni]) * g;
        }
      }
    }
}

extern "C" void kernel_launch(void* const* d_in, const int* in_sizes, int n_in,
                              void* d_out, int out_size, void* d_ws, size_t ws_size,
                              hipStream_t stream) {
  const float* x  = (const float*)d_in[0];
  const float* Wr = (const float*)d_in[1];
  const float* W1 = (const float*)d_in[2];
  const float* b1 = (const float*)d_in[3];
  const float* W2 = (const float*)d_in[4];
  const float* b2 = (const float*)d_in[5];
  float* out = (float*)d_out;

  char* ws = (char*)d_ws;
  float* probs_tok = (float*)ws;                        // 256 KB
  int* eidx   = (int*)(ws + 262144);                    // 32 KB
  float* gate = (float*)(ws + 262144 + 32768);          // 32 KB
  float* gatef = (float*)(ws + 262144 + 65536);         // 32 KB
  int* s2t    = (int*)(ws + 262144 + 98304);            // 40 KB
  int* kept   = (int*)(ws + 262144 + 139264);           // 32 KB
  char* big = ws + 448 * 1024;
  _Float16* gxb = (_Float16*)big;                                   // 20 MB
  _Float16* wt  = (_Float16*)(big + 20971520);                      // 64 MB (W1t, then W2t)
  _Float16* hb  = (_Float16*)(big + 20971520 + 67108864);           // 80 MB

  // fused W1-transpose (8192 blocks) + router (2048 blocks)
  pre_kernel<<<NEXP * 16 * 64 + NTOK / 4, 256, 0, stream>>>(
      x, Wr, W1, wt, eidx, gate, probs_tok);
  scan_kernel<<<1, 256, 0, stream>>>(eidx, gate, probs_tok, gatef, s2t, kept,
                                     out + (size_t)NTOK * DIMD);
  // fused gather (10240) + passthrough (8192)
  gp_kernel<<<NEXP * CAPD + NTOK, 256, 0, stream>>>(x, s2t, kept, gxb, out);
  gemm1_kernel<<<NEXP * 10 * 32, 256, 0, stream>>>(gxb, wt, b1, hb);
  transpose_cvt_kernel<<<NEXP * 64 * 16, 256, 0, stream>>>(W2, wt, DFFD, DIMD);
  gemm2_kernel<<<NEXP * 10 * 8, 256, 0, stream>>>(hb, wt, b2, s2t, gatef, out);
}

// Round 6
// 580.689 us; speedup vs baseline: 1.1754x; 1.0308x over previous
//
#include <hip/hip_runtime.h>
#include <stdint.h>

#define NTOK 8192
#define DIMD 1024
#define NEXP 8
#define DFFD 4096
#define CAPD 1280

typedef _Float16 half8_t __attribute__((ext_vector_type(8)));
typedef _Float16 half4_t __attribute__((ext_vector_type(4)));
typedef float float4_t __attribute__((ext_vector_type(4)));

typedef const __attribute__((address_space(1))) uint32_t* gas_ptr_t;
typedef __attribute__((address_space(3))) uint32_t* las_ptr_t;

__device__ __forceinline__ void async_ld16(void* lds, const void* g) {
  __builtin_amdgcn_global_load_lds((gas_ptr_t)g, (las_ptr_t)lds, 16, 0, 0);
}

__device__ __forceinline__ void wait4_barrier() {
  asm volatile("s_waitcnt vmcnt(4)\n\ts_barrier" ::: "memory");
}
__device__ __forceinline__ void wait0_barrier() {
  asm volatile("s_waitcnt vmcnt(0)\n\ts_barrier" ::: "memory");
}

__device__ __forceinline__ float gelu_f(float v) {
  // tanh-approx gelu (JAX default approximate=True)
  float u = 0.7978845608028654f * (v + 0.044715f * v * v * v);
  float t = 1.f - 2.f / (__expf(2.f * u) + 1.f);
  return 0.5f * v * (1.f + t);
}

// ---------------- transpose body: in [E][R][C] fp32 -> out [E][C][R] fp16 ----
__device__ __forceinline__ void transpose_body(
    const float* __restrict__ in, _Float16* __restrict__ out, int R, int C,
    int b, char* smem) {
  float (*tile)[65] = (float (*)[65])smem;
  int nC = C >> 6, nR = R >> 6;
  int e = b / (nR * nC);
  int rem = b % (nR * nC);
  int rt = rem / nC, ct = rem % nC;
  int tid = threadIdx.x;
  int r = tid >> 2, c0 = (tid & 3) * 16;
  const float* ip = in + (size_t)e * R * C + (size_t)(rt * 64 + r) * C + ct * 64 + c0;
#pragma unroll
  for (int j = 0; j < 4; j++) {
    float4 v = *(const float4*)(ip + j * 4);
    tile[r][c0 + j * 4 + 0] = v.x;
    tile[r][c0 + j * 4 + 1] = v.y;
    tile[r][c0 + j * 4 + 2] = v.z;
    tile[r][c0 + j * 4 + 3] = v.w;
  }
  __syncthreads();
  int c = tid >> 2, r0 = (tid & 3) * 16;
  half8_t o0, o1;
#pragma unroll
  for (int j = 0; j < 8; j++) {
    o0[j] = (_Float16)tile[r0 + j][c];
    o1[j] = (_Float16)tile[r0 + 8 + j][c];
  }
  _Float16* op = out + (size_t)e * C * R + (size_t)(ct * 64 + c) * R + rt * 64 + r0;
  *(half8_t*)op = o0;
  *(half8_t*)(op + 8) = o1;
}

// ---------------- router: logits, softmax, gate, argmax ----------------
__global__ __launch_bounds__(256) void router_kernel(
    const float* __restrict__ x, const float* __restrict__ Wr,
    int* __restrict__ eidx, float* __restrict__ gate,
    float* __restrict__ probs_tok) {
  __shared__ float wrt[NEXP * DIMD];  // transposed [e][d]
  int tid = threadIdx.x;
  for (int i = tid; i < NEXP * DIMD; i += 256) {
    int d = i >> 3, e = i & 7;
    wrt[e * DIMD + d] = Wr[i];
  }
  __syncthreads();
  int wave = tid >> 6, lane = tid & 63;
  int tok = blockIdx.x * 4 + wave;
  float acc[NEXP];
#pragma unroll
  for (int e = 0; e < NEXP; e++) acc[e] = 0.f;
  const float* xr = x + (size_t)tok * DIMD;
#pragma unroll
  for (int i = 0; i < DIMD / 64; i++) {
    int d = lane + i * 64;
    float xv = xr[d];
#pragma unroll
    for (int e = 0; e < NEXP; e++) acc[e] += xv * wrt[e * DIMD + d];
  }
#pragma unroll
  for (int off = 32; off >= 1; off >>= 1) {
#pragma unroll
    for (int e = 0; e < NEXP; e++) acc[e] += __shfl_xor(acc[e], off, 64);
  }
  float m = acc[0];
#pragma unroll
  for (int e = 1; e < NEXP; e++) m = fmaxf(m, acc[e]);
  float p[NEXP];
  float s = 0.f;
#pragma unroll
  for (int e = 0; e < NEXP; e++) { p[e] = __expf(acc[e] - m); s += p[e]; }
  float inv = 1.f / s;
  int ei = 0;
  float best = acc[0];
#pragma unroll
  for (int e = 1; e < NEXP; e++) { if (acc[e] > best) { best = acc[e]; ei = e; } }
  if (lane == 0) {
    eidx[tok] = ei;
    gate[tok] = p[ei] * inv;
    float4 pa = make_float4(p[0] * inv, p[1] * inv, p[2] * inv, p[3] * inv);
    float4 pb = make_float4(p[4] * inv, p[5] * inv, p[6] * inv, p[7] * inv);
    float4* pp = (float4*)(probs_tok + (size_t)tok * 8);
    pp[0] = pa;
    pp[1] = pb;
  }
}

// ---------------- ordered capacity scan body (runs in block 0) ----------------
__device__ __forceinline__ void scan_body(
    const int* __restrict__ eidx, const float* __restrict__ gate,
    const float* __restrict__ probs_tok, float* __restrict__ gatef,
    int* __restrict__ s2t, int* __restrict__ kept_out,
    float* __restrict__ aux_out, char* smem) {
  int (*cnt)[NEXP] = (int (*)[NEXP])smem;                    // 8192 B
  float (*ps)[NEXP] = (float (*)[NEXP])(smem + 8192);        // 8192 B
  int* tot = (int*)(smem + 16384);                           // 32 B
  float* psum_s = (float*)(smem + 16384 + 32);               // 32 B
  int tid = threadIdx.x;
  for (int i = tid; i < NEXP * CAPD; i += 256) s2t[i] = NTOK;
  float pa[NEXP];
#pragma unroll
  for (int k = 0; k < NEXP; k++) pa[k] = 0.f;
  for (int b = tid; b < NTOK; b += 256) {
    const float4* p = (const float4*)(probs_tok + (size_t)b * 8);
    float4 v0 = p[0], v1 = p[1];
    pa[0] += v0.x; pa[1] += v0.y; pa[2] += v0.z; pa[3] += v0.w;
    pa[4] += v1.x; pa[5] += v1.y; pa[6] += v1.z; pa[7] += v1.w;
  }
#pragma unroll
  for (int k = 0; k < NEXP; k++) ps[tid][k] = pa[k];
  int c[NEXP];
#pragma unroll
  for (int k = 0; k < NEXP; k++) c[k] = 0;
  int base = tid * 32;
  for (int i = 0; i < 32; i++) {
    int e = eidx[base + i];
#pragma unroll
    for (int k = 0; k < NEXP; k++) c[k] += (e == k);
  }
#pragma unroll
  for (int k = 0; k < NEXP; k++) cnt[tid][k] = c[k];
  __syncthreads();
  if (tid < NEXP) {
    int run = 0;
    for (int j = 0; j < 256; j++) { int v = cnt[j][tid]; cnt[j][tid] = run; run += v; }
    tot[tid] = run;
    float s = 0.f;
    for (int j = 0; j < 256; j++) s += ps[j][tid];
    psum_s[tid] = s;
  }
  __syncthreads();
  int off[NEXP];
#pragma unroll
  for (int k = 0; k < NEXP; k++) off[k] = cnt[tid][k];
  for (int i = 0; i < 32; i++) {
    int t2 = base + i;
    int e = eidx[t2];
    int pos = 0;
#pragma unroll
    for (int k = 0; k < NEXP; k++) pos += (e == k) ? off[k] : 0;
    bool kept = pos < CAPD;
    gatef[t2] = kept ? gate[t2] : 0.f;
    kept_out[t2] = kept ? 1 : 0;
    if (kept) s2t[e * CAPD + pos] = t2;
#pragma unroll
    for (int k = 0; k < NEXP; k++) off[k] += (e == k);
  }
  if (tid == 0) {
    float a = 0.f;
    for (int e = 0; e < NEXP; e++) {
      float tpe = (float)(tot[e] < CAPD ? tot[e] : CAPD);
      a += tpe * psum_s[e];
    }
    aux_out[0] = 0.01f * (float)NEXP * a / ((float)NTOK * (float)NTOK);
  }
}

// -------- fused: scan (block 0) + W1 transpose (blocks 1..8192) --------
// scan's single-CU serial latency hides under 8192 memory-bound transpose
// blocks; both depend only on router / input weights.
__global__ __launch_bounds__(256) void scan_w1t_kernel(
    const int* __restrict__ eidx, const float* __restrict__ gate,
    const float* __restrict__ probs_tok, float* __restrict__ gatef,
    int* __restrict__ s2t, int* __restrict__ kept_out,
    float* __restrict__ aux_out,
    const float* __restrict__ W1, _Float16* __restrict__ w1t) {
  __shared__ __align__(16) char smem[16640];
  int b = blockIdx.x;
  if (b == 0) {
    scan_body(eidx, gate, probs_tok, gatef, s2t, kept_out, aux_out, smem);
  } else {
    transpose_body(W1, w1t, DIMD, DFFD, b - 1, smem);
  }
}

// ---- plain transpose kernel (fallback path only) ----
__global__ __launch_bounds__(256) void transpose_cvt_kernel(
    const float* __restrict__ in, _Float16* __restrict__ out, int R, int C) {
  __shared__ __align__(16) char smem[64 * 65 * 4];
  transpose_body(in, out, R, C, blockIdx.x, smem);
}

// -------- fused: gather (blocks 0..10239) + passthrough (10240..18431) --------
__global__ __launch_bounds__(256) void gp_kernel(
    const float* __restrict__ x, const int* __restrict__ s2t,
    const int* __restrict__ kept, _Float16* __restrict__ gxb,
    float* __restrict__ out) {
  int b = blockIdx.x;
  int tid = threadIdx.x;
  if (b < NEXP * CAPD) {
    int tok = s2t[b];
    half4_t o;
    if (tok < NTOK) {
      float4 v = *(const float4*)(x + (size_t)tok * DIMD + tid * 4);
      o[0] = (_Float16)v.x; o[1] = (_Float16)v.y;
      o[2] = (_Float16)v.z; o[3] = (_Float16)v.w;
    } else {
      o[0] = o[1] = o[2] = o[3] = (_Float16)0.f;
    }
    *(half4_t*)(gxb + (size_t)b * DIMD + tid * 4) = o;
  } else {
    int tok = b - NEXP * CAPD;
    if (kept[tok]) return;
    *(float4*)(out + (size_t)tok * DIMD + tid * 4) =
        *(const float4*)(x + (size_t)tok * DIMD + tid * 4);
  }
}

// -------- 128x128 phase-fenced MFMA GEMM core, 3-slot ring, depth-2 --------
// (R4-verified; unchanged.) C[128x128] += A[128xK] * B^T[128xK]. 256 threads
// = 4 waves (2Mx2N), wave 64x64 (4x4 16x16 frags), BK=32. 3-slot LDS ring
// (48 KB -> 3 blocks/CU). Depth-2 prefetch; vmcnt(4) at tile end lands tile
// t+1, keeps t+2 in flight. Phase fence: {8 ds_reads | 4 stage -> s_barrier
// -> lgkmcnt(0)+sched_barrier -> setprio(1) -> 16 MFMA -> setprio(0) ->
// counted barrier}. XOR swizzle q^((row>>1)&3) on global source + LDS reads.
template <int KD>
__device__ __forceinline__ void gemm_core128(const _Float16* __restrict__ A,
                                             const _Float16* __restrict__ B,
                                             _Float16* buf, float4_t acc[4][4]) {
  const int tid = threadIdx.x;  // 0..255
  const _Float16* gp[4];
  int lofs[4];
#pragma unroll
  for (int j = 0; j < 2; ++j) {
    int elem = j * 2048 + tid * 8;   // halfs within a 128x32 matrix
    int row = elem >> 5;
    int q = (elem >> 3) & 3;
    int qs = q ^ ((row >> 1) & 3);   // inverse-swizzled source chunk
    gp[j] = A + (size_t)row * KD + qs * 8;
    gp[2 + j] = B + (size_t)row * KD + qs * 8;
    lofs[j] = elem;             // A region of slot
    lofs[2 + j] = 4096 + elem;  // B region of slot
  }
  const int lane = tid & 63;
  const int wid = tid >> 6;
  const int wm = (wid >> 1) * 64, wn = (wid & 1) * 64;
  const int lr = lane & 15;
  const int ko = ((lane >> 4) ^ ((lr >> 1) & 3)) * 8;
  constexpr int KT = KD / 32;
  // prologue: stage tile 0 -> slot 0, tile 1 -> slot 1
#pragma unroll
  for (int j = 0; j < 4; ++j) async_ld16(buf + lofs[j], gp[j]);
#pragma unroll
  for (int j = 0; j < 4; ++j) {
    async_ld16(buf + 8192 + lofs[j], gp[j] + 32);
    gp[j] += 64;
  }
  wait4_barrier();  // tile 0 landed everywhere; tile 1 still in flight
  int sc = 0, sp = 2;  // current slot, prefetch slot = (t+2)%3
#pragma unroll 1
  for (int t = 0; t < KT; ++t) {
    const _Float16* As = buf + sc * 8192;
    const _Float16* Bs = As + 4096;
    const bool pf = (t + 2 < KT);
    half8_t a[4], b[4];
#pragma unroll
    for (int i = 0; i < 4; ++i)
      b[i] = *(const half8_t*)(Bs + (wn + i * 16 + lr) * 32 + ko);
#pragma unroll
    for (int i = 0; i < 4; ++i)
      a[i] = *(const half8_t*)(As + (wm + i * 16 + lr) * 32 + ko);
    if (pf) {
      _Float16* dst = buf + sp * 8192;
#pragma unroll
      for (int j = 0; j < 4; ++j) { async_ld16(dst + lofs[j], gp[j]); gp[j] += 32; }
    }
    __builtin_amdgcn_s_barrier();
    asm volatile("s_waitcnt lgkmcnt(0)" ::: "memory");
    __builtin_amdgcn_sched_barrier(0);
    __builtin_amdgcn_s_setprio(1);
#pragma unroll
    for (int mi = 0; mi < 4; ++mi)
#pragma unroll
      for (int ni = 0; ni < 4; ++ni)
        acc[mi][ni] =
            __builtin_amdgcn_mfma_f32_16x16x32_f16(a[mi], b[ni], acc[mi][ni], 0, 0, 0);
    __builtin_amdgcn_s_setprio(0);
    if (pf) wait4_barrier(); else wait0_barrier();
    sc = (sc == 2) ? 0 : sc + 1;
    sp = (sp == 2) ? 0 : sp + 1;
  }
}

// ---- GEMM1 (+ optionally fused W2 transpose in trailing blocks) ----
// blocks [0, ngemm): h = gelu(gx @ W1 + b1); blocks [ngemm, ...): W2->w2t.
// gemm1 runs at ~18% HBM, ~30% MFMA -> the memory-bound transpose rides in
// its bandwidth shadow instead of a serial ~50us slot.
__global__ __launch_bounds__(256, 3) void gemm1_kernel(
    const _Float16* __restrict__ gxb, const _Float16* __restrict__ w1t,
    const float* __restrict__ b1, _Float16* __restrict__ hb,
    const float* __restrict__ W2, _Float16* __restrict__ w2t, int ngemm) {
  __shared__ __align__(16) _Float16 buf[24576];  // 48 KB (transpose aliases)
  int bx = blockIdx.x;
  if (bx >= ngemm) {
    transpose_body(W2, w2t, DFFD, DIMD, bx - ngemm, (char*)buf);
    return;
  }
  // XCD-aware bijective swizzle over the gemm sub-grid (2560 = 8*320)
  int blk = (bx & 7) * (ngemm >> 3) + (bx >> 3);
  int e = blk / 320;
  int rem = blk % 320;
  // mb fastest: concurrent blocks share nb's B-panel while the expert's
  // whole A (2.5 MB) stays resident in the 4 MB XCD-L2 (R5: FETCH 300->94MB)
  int mb = rem % 10, nb = rem / 10;
  const _Float16* A = gxb + (size_t)e * CAPD * DIMD + (size_t)mb * 128 * DIMD;
  const _Float16* B = w1t + (size_t)e * DFFD * DIMD + (size_t)nb * 128 * DIMD;
  float4_t acc[4][4];
#pragma unroll
  for (int mi = 0; mi < 4; ++mi)
#pragma unroll
    for (int ni = 0; ni < 4; ++ni) acc[mi][ni] = (float4_t){0.f, 0.f, 0.f, 0.f};
  gemm_core128<DIMD>(A, B, buf, acc);
  const int tid = threadIdx.x;
  const int lane = tid & 63;
  const int wid = tid >> 6;
  const int wm = (wid >> 1) * 64, wn = (wid & 1) * 64;
  const int l15 = lane & 15, q4 = (lane >> 4) * 4;
  float bias[4];
#pragma unroll
  for (int ni = 0; ni < 4; ++ni) bias[ni] = b1[e * DFFD + nb * 128 + wn + ni * 16 + l15];
  _Float16* hrow = hb + (size_t)e * CAPD * DFFD + (size_t)(mb * 128) * DFFD + nb * 128;
#pragma unroll
  for (int mi = 0; mi < 4; ++mi)
#pragma unroll
    for (int ni = 0; ni < 4; ++ni)
#pragma unroll
      for (int r = 0; r < 4; ++r) {
        int row = wm + mi * 16 + q4 + r;
        int col = wn + ni * 16 + l15;
        float v = acc[mi][ni][r] + bias[ni];
        hrow[(size_t)row * DFFD + col] = (_Float16)gelu_f(v);
      }
}

// ---------------- GEMM2: final[tok] = (h @ W2 + b2) * gate ----------------
__global__ __launch_bounds__(256, 3) void gemm2_kernel(
    const _Float16* __restrict__ hb, const _Float16* __restrict__ w2t,
    const float* __restrict__ b2, const int* __restrict__ s2t,
    const float* __restrict__ gatef, float* __restrict__ outp) {
  __shared__ __align__(16) _Float16 buf[24576];  // 48 KB 3-slot ring
  __shared__ int tok_s[128];
  __shared__ float gate_s[128];
  // XCD-aware bijective swizzle (grid = 640 = 8*80; one expert per XCD)
  int nwg = gridDim.x;
  int bx = blockIdx.x;
  int blk = (bx & 7) * (nwg >> 3) + (bx >> 3);
  int e = blk / 80;
  int rem = blk % 80;
  int mb = rem / 8, nb = rem % 8;
  int tid = threadIdx.x;
  if (tid < 128) {
    int tok = s2t[e * CAPD + mb * 128 + tid];
    tok_s[tid] = tok;
    gate_s[tid] = (tok < NTOK) ? gatef[tok] : 0.f;
  }
  __syncthreads();  // drains all vmem before the counted-vmcnt core
  const _Float16* A = hb + (size_t)e * CAPD * DFFD + (size_t)mb * 128 * DFFD;
  const _Float16* B = w2t + (size_t)e * DIMD * DFFD + (size_t)nb * 128 * DFFD;
  float4_t acc[4][4];
#pragma unroll
  for (int mi = 0; mi < 4; ++mi)
#pragma unroll
    for (int ni = 0; ni < 4; ++ni) acc[mi][ni] = (float4_t){0.f, 0.f, 0.f, 0.f};
  gemm_core128<DFFD>(A, B, buf, acc);
  const int lane = tid & 63;
  const int wid = tid >> 6;
  const int wm = (wid >> 1) * 64, wn = (wid & 1) * 64;
  const int l15 = lane & 15, q4 = (lane >> 4) * 4;
  float bias[4];
#pragma unroll
  for (int ni = 0; ni < 4; ++ni) bias[ni] = b2[e * DIMD + nb * 128 + wn + ni * 16 + l15];
#pragma unroll
  for (int mi = 0; mi < 4; ++mi)
#pragma unroll
    for (int r = 0; r < 4; ++r) {
      int row = wm + mi * 16 + q4 + r;
      int tok = tok_s[row];
      float g = gate_s[row];
      if (tok < NTOK) {
#pragma unroll
        for (int ni = 0; ni < 4; ++ni) {
          int col = nb * 128 + wn + ni * 16 + l15;
          outp[(size_t)tok * DIMD + col] = (acc[mi][ni][r] + bias[ni]) * g;
        }
      }
    }
}

extern "C" void kernel_launch(void* const* d_in, const int* in_sizes, int n_in,
                              void* d_out, int out_size, void* d_ws, size_t ws_size,
                              hipStream_t stream) {
  const float* x  = (const float*)d_in[0];
  const float* Wr = (const float*)d_in[1];
  const float* W1 = (const float*)d_in[2];
  const float* b1 = (const float*)d_in[3];
  const float* W2 = (const float*)d_in[4];
  const float* b2 = (const float*)d_in[5];
  float* out = (float*)d_out;

  char* ws = (char*)d_ws;
  float* probs_tok = (float*)ws;                        // 256 KB
  int* eidx   = (int*)(ws + 262144);                    // 32 KB
  float* gate = (float*)(ws + 262144 + 32768);          // 32 KB
  float* gatef = (float*)(ws + 262144 + 65536);         // 32 KB
  int* s2t    = (int*)(ws + 262144 + 98304);            // 40 KB
  int* kept   = (int*)(ws + 262144 + 139264);           // 32 KB
  char* big = ws + 448 * 1024;

  const size_t MB = 1024 * 1024;
  _Float16* gxb = (_Float16*)big;                       // 20 MiB
  _Float16* w1t = (_Float16*)(big + 20 * MB);           // 64 MiB
  // Overlapped path needs a separate 64 MiB w2t so the W2 transpose can run
  // concurrently with gemm1 (which reads w1t). Fallback aliases w2t=w1t and
  // transposes sequentially (exact R5 behavior).
  size_t need = 448 * 1024 + (20 + 64 + 64 + 80) * MB;
  bool overlap = (ws_size >= need);
  _Float16* w2t = overlap ? (_Float16*)(big + 84 * MB) : w1t;
  _Float16* hb  = overlap ? (_Float16*)(big + 148 * MB)
                          : (_Float16*)(big + 84 * MB); // 80 MiB

  const int NG1 = NEXP * 10 * 32;   // 2560 gemm1 blocks
  const int NTR = NEXP * 16 * 64;   // 8192 transpose tiles (same count both W)

  router_kernel<<<NTOK / 4, 256, 0, stream>>>(x, Wr, eidx, gate, probs_tok);
  // scan (1 block) + W1 transpose (8192 blocks) in one launch
  scan_w1t_kernel<<<1 + NTR, 256, 0, stream>>>(
      eidx, gate, probs_tok, gatef, s2t, kept, out + (size_t)NTOK * DIMD,
      W1, w1t);
  // gather (10240) + passthrough (8192)
  gp_kernel<<<NEXP * CAPD + NTOK, 256, 0, stream>>>(x, s2t, kept, gxb, out);
  if (overlap) {
    gemm1_kernel<<<NG1 + NTR, 256, 0, stream>>>(gxb, w1t, b1, hb, W2, w2t, NG1);
  } else {
    gemm1_kernel<<<NG1, 256, 0, stream>>>(gxb, w1t, b1, hb, W2, w2t, NG1);
    transpose_cvt_kernel<<<NTR, 256, 0, stream>>>(W2, w2t, DFFD, DIMD);
  }
  gemm2_kernel<<<NEXP * 10 * 8, 256, 0, stream>>>(hb, w2t, b2, s2t, gatef, out);
}

// Round 7
// 578.105 us; speedup vs baseline: 1.1807x; 1.0045x over previous
//
#include <hip/hip_runtime.h>
#include <stdint.h>

#define NTOK 8192
#define DIMD 1024
#define NEXP 8
#define DFFD 4096
#define CAPD 1280

typedef _Float16 half8_t __attribute__((ext_vector_type(8)));
typedef _Float16 half4_t __attribute__((ext_vector_type(4)));
typedef float float4_t __attribute__((ext_vector_type(4)));

typedef const __attribute__((address_space(1))) uint32_t* gas_ptr_t;
typedef __attribute__((address_space(3))) uint32_t* las_ptr_t;

__device__ __forceinline__ void async_ld16(void* lds, const void* g) {
  __builtin_amdgcn_global_load_lds((gas_ptr_t)g, (las_ptr_t)lds, 16, 0, 0);
}

// Counted-vmcnt barriers: wait only the oldest outstanding global_load_lds
// groups, keep the newest prefetch in flight across the workgroup barrier.
__device__ __forceinline__ void wait4_barrier() {
  asm volatile("s_waitcnt vmcnt(4)\n\ts_barrier" ::: "memory");
}
__device__ __forceinline__ void wait6_barrier() {
  asm volatile("s_waitcnt vmcnt(6)\n\ts_barrier" ::: "memory");
}
__device__ __forceinline__ void wait0_barrier() {
  asm volatile("s_waitcnt vmcnt(0)\n\ts_barrier" ::: "memory");
}

__device__ __forceinline__ float gelu_f(float v) {
  // tanh-approx gelu (JAX default approximate=True)
  float u = 0.7978845608028654f * (v + 0.044715f * v * v * v);
  float t = 1.f - 2.f / (__expf(2.f * u) + 1.f);
  return 0.5f * v * (1.f + t);
}

// ---------------- transpose body: in [E][R][C] fp32 -> out [E][C][R] fp16 ----
__device__ __forceinline__ void transpose_body(
    const float* __restrict__ in, _Float16* __restrict__ out, int R, int C,
    int b, char* smem) {
  float (*tile)[65] = (float (*)[65])smem;
  int nC = C >> 6, nR = R >> 6;
  int e = b / (nR * nC);
  int rem = b % (nR * nC);
  int rt = rem / nC, ct = rem % nC;
  int tid = threadIdx.x;
  int r = tid >> 2, c0 = (tid & 3) * 16;
  const float* ip = in + (size_t)e * R * C + (size_t)(rt * 64 + r) * C + ct * 64 + c0;
#pragma unroll
  for (int j = 0; j < 4; j++) {
    float4 v = *(const float4*)(ip + j * 4);
    tile[r][c0 + j * 4 + 0] = v.x;
    tile[r][c0 + j * 4 + 1] = v.y;
    tile[r][c0 + j * 4 + 2] = v.z;
    tile[r][c0 + j * 4 + 3] = v.w;
  }
  __syncthreads();
  int c = tid >> 2, r0 = (tid & 3) * 16;
  half8_t o0, o1;
#pragma unroll
  for (int j = 0; j < 8; j++) {
    o0[j] = (_Float16)tile[r0 + j][c];
    o1[j] = (_Float16)tile[r0 + 8 + j][c];
  }
  _Float16* op = out + (size_t)e * C * R + (size_t)(ct * 64 + c) * R + rt * 64 + r0;
  *(half8_t*)op = o0;
  *(half8_t*)(op + 8) = o1;
}

// ---------------- router: logits, softmax, gate, argmax ----------------
__global__ __launch_bounds__(256) void router_kernel(
    const float* __restrict__ x, const float* __restrict__ Wr,
    int* __restrict__ eidx, float* __restrict__ gate,
    float* __restrict__ probs_tok) {
  __shared__ float wrt[NEXP * DIMD];  // transposed [e][d]
  int tid = threadIdx.x;
  for (int i = tid; i < NEXP * DIMD; i += 256) {
    int d = i >> 3, e = i & 7;
    wrt[e * DIMD + d] = Wr[i];
  }
  __syncthreads();
  int wave = tid >> 6, lane = tid & 63;
  int tok = blockIdx.x * 4 + wave;
  float acc[NEXP];
#pragma unroll
  for (int e = 0; e < NEXP; e++) acc[e] = 0.f;
  const float* xr = x + (size_t)tok * DIMD;
#pragma unroll
  for (int i = 0; i < DIMD / 64; i++) {
    int d = lane + i * 64;
    float xv = xr[d];
#pragma unroll
    for (int e = 0; e < NEXP; e++) acc[e] += xv * wrt[e * DIMD + d];
  }
#pragma unroll
  for (int off = 32; off >= 1; off >>= 1) {
#pragma unroll
    for (int e = 0; e < NEXP; e++) acc[e] += __shfl_xor(acc[e], off, 64);
  }
  float m = acc[0];
#pragma unroll
  for (int e = 1; e < NEXP; e++) m = fmaxf(m, acc[e]);
  float p[NEXP];
  float s = 0.f;
#pragma unroll
  for (int e = 0; e < NEXP; e++) { p[e] = __expf(acc[e] - m); s += p[e]; }
  float inv = 1.f / s;
  int ei = 0;
  float best = acc[0];
#pragma unroll
  for (int e = 1; e < NEXP; e++) { if (acc[e] > best) { best = acc[e]; ei = e; } }
  if (lane == 0) {
    eidx[tok] = ei;
    gate[tok] = p[ei] * inv;
    float4 pa = make_float4(p[0] * inv, p[1] * inv, p[2] * inv, p[3] * inv);
    float4 pb = make_float4(p[4] * inv, p[5] * inv, p[6] * inv, p[7] * inv);
    float4* pp = (float4*)(probs_tok + (size_t)tok * 8);
    pp[0] = pa;
    pp[1] = pb;
  }
}

// ---------------- ordered capacity scan body (runs in block 0) ----------------
__device__ __forceinline__ void scan_body(
    const int* __restrict__ eidx, const float* __restrict__ gate,
    const float* __restrict__ probs_tok, float* __restrict__ gatef,
    int* __restrict__ s2t, int* __restrict__ kept_out,
    float* __restrict__ aux_out, char* smem) {
  int (*cnt)[NEXP] = (int (*)[NEXP])smem;                    // 8192 B
  float (*ps)[NEXP] = (float (*)[NEXP])(smem + 8192);        // 8192 B
  int* tot = (int*)(smem + 16384);                           // 32 B
  float* psum_s = (float*)(smem + 16384 + 32);               // 32 B
  int tid = threadIdx.x;
  for (int i = tid; i < NEXP * CAPD; i += 256) s2t[i] = NTOK;
  float pa[NEXP];
#pragma unroll
  for (int k = 0; k < NEXP; k++) pa[k] = 0.f;
  for (int b = tid; b < NTOK; b += 256) {
    const float4* p = (const float4*)(probs_tok + (size_t)b * 8);
    float4 v0 = p[0], v1 = p[1];
    pa[0] += v0.x; pa[1] += v0.y; pa[2] += v0.z; pa[3] += v0.w;
    pa[4] += v1.x; pa[5] += v1.y; pa[6] += v1.z; pa[7] += v1.w;
  }
#pragma unroll
  for (int k = 0; k < NEXP; k++) ps[tid][k] = pa[k];
  int c[NEXP];
#pragma unroll
  for (int k = 0; k < NEXP; k++) c[k] = 0;
  int base = tid * 32;
  for (int i = 0; i < 32; i++) {
    int e = eidx[base + i];
#pragma unroll
    for (int k = 0; k < NEXP; k++) c[k] += (e == k);
  }
#pragma unroll
  for (int k = 0; k < NEXP; k++) cnt[tid][k] = c[k];
  __syncthreads();
  if (tid < NEXP) {
    int run = 0;
    for (int j = 0; j < 256; j++) { int v = cnt[j][tid]; cnt[j][tid] = run; run += v; }
    tot[tid] = run;
    float s = 0.f;
    for (int j = 0; j < 256; j++) s += ps[j][tid];
    psum_s[tid] = s;
  }
  __syncthreads();
  int off[NEXP];
#pragma unroll
  for (int k = 0; k < NEXP; k++) off[k] = cnt[tid][k];
  for (int i = 0; i < 32; i++) {
    int t2 = base + i;
    int e = eidx[t2];
    int pos = 0;
#pragma unroll
    for (int k = 0; k < NEXP; k++) pos += (e == k) ? off[k] : 0;
    bool kept = pos < CAPD;
    gatef[t2] = kept ? gate[t2] : 0.f;
    kept_out[t2] = kept ? 1 : 0;
    if (kept) s2t[e * CAPD + pos] = t2;
#pragma unroll
    for (int k = 0; k < NEXP; k++) off[k] += (e == k);
  }
  if (tid == 0) {
    float a = 0.f;
    for (int e = 0; e < NEXP; e++) {
      float tpe = (float)(tot[e] < CAPD ? tot[e] : CAPD);
      a += tpe * psum_s[e];
    }
    aux_out[0] = 0.01f * (float)NEXP * a / ((float)NTOK * (float)NTOK);
  }
}

// -------- fused: scan (block 0) + W1 transpose (blocks 1..8192) --------
__global__ __launch_bounds__(256) void scan_w1t_kernel(
    const int* __restrict__ eidx, const float* __restrict__ gate,
    const float* __restrict__ probs_tok, float* __restrict__ gatef,
    int* __restrict__ s2t, int* __restrict__ kept_out,
    float* __restrict__ aux_out,
    const float* __restrict__ W1, _Float16* __restrict__ w1t) {
  __shared__ __align__(16) char smem[16640];
  int b = blockIdx.x;
  if (b == 0) {
    scan_body(eidx, gate, probs_tok, gatef, s2t, kept_out, aux_out, smem);
  } else {
    transpose_body(W1, w1t, DIMD, DFFD, b - 1, smem);
  }
}

// ---- plain transpose kernel (fallback path only) ----
__global__ __launch_bounds__(256) void transpose_cvt_kernel(
    const float* __restrict__ in, _Float16* __restrict__ out, int R, int C) {
  __shared__ __align__(16) char smem[64 * 65 * 4];
  transpose_body(in, out, R, C, blockIdx.x, smem);
}

// -------- fused: gather (blocks 0..10239) + passthrough (10240..18431) --------
__global__ __launch_bounds__(256) void gp_kernel(
    const float* __restrict__ x, const int* __restrict__ s2t,
    const int* __restrict__ kept, _Float16* __restrict__ gxb,
    float* __restrict__ out) {
  int b = blockIdx.x;
  int tid = threadIdx.x;
  if (b < NEXP * CAPD) {
    int tok = s2t[b];
    half4_t o;
    if (tok < NTOK) {
      float4 v = *(const float4*)(x + (size_t)tok * DIMD + tid * 4);
      o[0] = (_Float16)v.x; o[1] = (_Float16)v.y;
      o[2] = (_Float16)v.z; o[3] = (_Float16)v.w;
    } else {
      o[0] = o[1] = o[2] = o[3] = (_Float16)0.f;
    }
    *(half4_t*)(gxb + (size_t)b * DIMD + tid * 4) = o;
  } else {
    int tok = b - NEXP * CAPD;
    if (kept[tok]) return;
    *(float4*)(out + (size_t)tok * DIMD + tid * 4) =
        *(const float4*)(x + (size_t)tok * DIMD + tid * 4);
  }
}

// -------- 128x128 phase-fenced MFMA GEMM core, 3-slot ring, depth-2 --------
// (R4-verified; unchanged — used by gemm2.) 256 threads = 4 waves (2Mx2N),
// wave 64x64 (4x4 frags), BK=32. 48 KB ring -> 3 blocks/CU. vmcnt(4) at
// tile end lands t+1, keeps t+2 in flight. XOR swizzle q^((row>>1)&3).
template <int KD>
__device__ __forceinline__ void gemm_core128(const _Float16* __restrict__ A,
                                             const _Float16* __restrict__ B,
                                             _Float16* buf, float4_t acc[4][4]) {
  const int tid = threadIdx.x;  // 0..255
  const _Float16* gp[4];
  int lofs[4];
#pragma unroll
  for (int j = 0; j < 2; ++j) {
    int elem = j * 2048 + tid * 8;   // halfs within a 128x32 matrix
    int row = elem >> 5;
    int q = (elem >> 3) & 3;
    int qs = q ^ ((row >> 1) & 3);   // inverse-swizzled source chunk
    gp[j] = A + (size_t)row * KD + qs * 8;
    gp[2 + j] = B + (size_t)row * KD + qs * 8;
    lofs[j] = elem;             // A region of slot
    lofs[2 + j] = 4096 + elem;  // B region of slot
  }
  const int lane = tid & 63;
  const int wid = tid >> 6;
  const int wm = (wid >> 1) * 64, wn = (wid & 1) * 64;
  const int lr = lane & 15;
  const int ko = ((lane >> 4) ^ ((lr >> 1) & 3)) * 8;
  constexpr int KT = KD / 32;
#pragma unroll
  for (int j = 0; j < 4; ++j) async_ld16(buf + lofs[j], gp[j]);
#pragma unroll
  for (int j = 0; j < 4; ++j) {
    async_ld16(buf + 8192 + lofs[j], gp[j] + 32);
    gp[j] += 64;
  }
  wait4_barrier();  // tile 0 landed everywhere; tile 1 still in flight
  int sc = 0, sp = 2;
#pragma unroll 1
  for (int t = 0; t < KT; ++t) {
    const _Float16* As = buf + sc * 8192;
    const _Float16* Bs = As + 4096;
    const bool pf = (t + 2 < KT);
    half8_t a[4], b[4];
#pragma unroll
    for (int i = 0; i < 4; ++i)
      b[i] = *(const half8_t*)(Bs + (wn + i * 16 + lr) * 32 + ko);
#pragma unroll
    for (int i = 0; i < 4; ++i)
      a[i] = *(const half8_t*)(As + (wm + i * 16 + lr) * 32 + ko);
    if (pf) {
      _Float16* dst = buf + sp * 8192;
#pragma unroll
      for (int j = 0; j < 4; ++j) { async_ld16(dst + lofs[j], gp[j]); gp[j] += 32; }
    }
    __builtin_amdgcn_s_barrier();
    asm volatile("s_waitcnt lgkmcnt(0)" ::: "memory");
    __builtin_amdgcn_sched_barrier(0);
    __builtin_amdgcn_s_setprio(1);
#pragma unroll
    for (int mi = 0; mi < 4; ++mi)
#pragma unroll
      for (int ni = 0; ni < 4; ++ni)
        acc[mi][ni] =
            __builtin_amdgcn_mfma_f32_16x16x32_f16(a[mi], b[ni], acc[mi][ni], 0, 0, 0);
    __builtin_amdgcn_s_setprio(0);
    if (pf) wait4_barrier(); else wait0_barrier();
    sc = (sc == 2) ? 0 : sc + 1;
    sp = (sp == 2) ? 0 : sp + 1;
  }
}

// -------- 256x128 phase-fenced MFMA GEMM core, 3-slot ring, depth-2 --------
// C[256x128] += A[256xK] * B^T[128xK]. 256 threads = 4 waves (2Mx2N), wave
// tile 128x64 (8x4 frags, 32 MFMA/K-tile). +33% FLOP per LDS byte vs 128²
// (12 ds_read_b128 per 32 MFMA vs 8 per 16) and half the barriers per FLOP.
// LDS: slot = A 256x32 (16KB) + B 128x32 (8KB) = 24 KB; 3-slot ring 72 KB
// -> 2 blocks/CU (VGPR ~210 -> 2 waves/SIMD, consistent).
// Ledger: 6 loads/tile (4 A + 2 B chunks per thread). Prologue stages t0,t1
// (12 outstanding) -> vmcnt(6) = t0 landed. Iter t stages t+2 (12 out) ->
// vmcnt(6) at end = t+1 landed, t+2 in flight. Tail (pf=false): wait0.
// Same XOR swizzle q^((row>>1)&3) on source + ds_read (rows mod 8 residues
// identical for rows 128..255 -> conflict-free property preserved).
template <int KD>
__device__ __forceinline__ void gemm_core256x128(const _Float16* __restrict__ A,
                                                 const _Float16* __restrict__ B,
                                                 _Float16* buf, float4_t acc[8][4]) {
  const int tid = threadIdx.x;  // 0..255
  const _Float16* gp[6];
  int lofs[6];
#pragma unroll
  for (int j = 0; j < 4; ++j) {  // A: 256x32 = 8192 halfs, 4 chunks/thread
    int elem = j * 2048 + tid * 8;
    int row = elem >> 5;
    int q = (elem >> 3) & 3;
    int qs = q ^ ((row >> 1) & 3);
    gp[j] = A + (size_t)row * KD + qs * 8;
    lofs[j] = elem;
  }
#pragma unroll
  for (int j = 0; j < 2; ++j) {  // B: 128x32 = 4096 halfs, 2 chunks/thread
    int elem = j * 2048 + tid * 8;
    int row = elem >> 5;
    int q = (elem >> 3) & 3;
    int qs = q ^ ((row >> 1) & 3);
    gp[4 + j] = B + (size_t)row * KD + qs * 8;
    lofs[4 + j] = 8192 + elem;  // B region after 16KB A region
  }
  const int lane = tid & 63;
  const int wid = tid >> 6;
  const int wm = (wid >> 1) * 128, wn = (wid & 1) * 64;
  const int lr = lane & 15;
  const int ko = ((lane >> 4) ^ ((lr >> 1) & 3)) * 8;
  constexpr int KT = KD / 32;
  // prologue: stage tile 0 -> slot 0, tile 1 -> slot 1
#pragma unroll
  for (int j = 0; j < 6; ++j) async_ld16(buf + lofs[j], gp[j]);
#pragma unroll
  for (int j = 0; j < 6; ++j) {
    async_ld16(buf + 12288 + lofs[j], gp[j] + 32);
    gp[j] += 64;
  }
  wait6_barrier();  // tile 0 landed; tile 1's 6 loads still in flight
  int sc = 0, sp = 2;
#pragma unroll 1
  for (int t = 0; t < KT; ++t) {
    const _Float16* As = buf + sc * 12288;
    const _Float16* Bs = As + 8192;
    const bool pf = (t + 2 < KT);
    half8_t a[8], b[4];
#pragma unroll
    for (int i = 0; i < 4; ++i)
      b[i] = *(const half8_t*)(Bs + (wn + i * 16 + lr) * 32 + ko);
#pragma unroll
    for (int i = 0; i < 8; ++i)
      a[i] = *(const half8_t*)(As + (wm + i * 16 + lr) * 32 + ko);
    if (pf) {
      _Float16* dst = buf + sp * 12288;
#pragma unroll
      for (int j = 0; j < 6; ++j) { async_ld16(dst + lofs[j], gp[j]); gp[j] += 32; }
    }
    __builtin_amdgcn_s_barrier();
    asm volatile("s_waitcnt lgkmcnt(0)" ::: "memory");
    __builtin_amdgcn_sched_barrier(0);
    __builtin_amdgcn_s_setprio(1);
#pragma unroll
    for (int mi = 0; mi < 8; ++mi)
#pragma unroll
      for (int ni = 0; ni < 4; ++ni)
        acc[mi][ni] =
            __builtin_amdgcn_mfma_f32_16x16x32_f16(a[mi], b[ni], acc[mi][ni], 0, 0, 0);
    __builtin_amdgcn_s_setprio(0);
    if (pf) wait6_barrier(); else wait0_barrier();
    sc = (sc == 2) ? 0 : sc + 1;
    sp = (sp == 2) ? 0 : sp + 1;
  }
}

// ---- GEMM1 (256x128 tiles) + fused W2 transpose in trailing blocks ----
// blocks [0, ngemm): h = gelu(gx @ W1 + b1); blocks [ngemm, ...): W2->w2t.
__global__ __launch_bounds__(256, 2) void gemm1_kernel(
    const _Float16* __restrict__ gxb, const _Float16* __restrict__ w1t,
    const float* __restrict__ b1, _Float16* __restrict__ hb,
    const float* __restrict__ W2, _Float16* __restrict__ w2t, int ngemm) {
  __shared__ __align__(16) _Float16 buf[36864];  // 72 KB 3-slot ring
  int bx = blockIdx.x;
  if (bx >= ngemm) {
    transpose_body(W2, w2t, DFFD, DIMD, bx - ngemm, (char*)buf);
    return;
  }
  // XCD-aware bijective swizzle over the gemm sub-grid (1280 = 8*160)
  int blk = (bx & 7) * (ngemm >> 3) + (bx >> 3);
  int e = blk / 160;            // 5 M-tiles x 32 N-tiles per expert
  int rem = blk % 160;
  // mb fastest: expert's whole A (2.5 MB) stays in the 4 MB XCD-L2 while
  // concurrent blocks share nb's B-panel (R5 FETCH-verified: 300->94 MB).
  int mb = rem % 5, nb = rem / 5;
  const _Float16* A = gxb + (size_t)e * CAPD * DIMD + (size_t)mb * 256 * DIMD;
  const _Float16* B = w1t + (size_t)e * DFFD * DIMD + (size_t)nb * 128 * DIMD;
  float4_t acc[8][4];
#pragma unroll
  for (int mi = 0; mi < 8; ++mi)
#pragma unroll
    for (int ni = 0; ni < 4; ++ni) acc[mi][ni] = (float4_t){0.f, 0.f, 0.f, 0.f};
  gemm_core256x128<DIMD>(A, B, buf, acc);
  const int tid = threadIdx.x;
  const int lane = tid & 63;
  const int wid = tid >> 6;
  const int wm = (wid >> 1) * 128, wn = (wid & 1) * 64;
  const int l15 = lane & 15, q4 = (lane >> 4) * 4;
  float bias[4];
#pragma unroll
  for (int ni = 0; ni < 4; ++ni) bias[ni] = b1[e * DFFD + nb * 128 + wn + ni * 16 + l15];
  _Float16* hrow = hb + (size_t)e * CAPD * DFFD + (size_t)(mb * 256) * DFFD + nb * 128;
#pragma unroll
  for (int mi = 0; mi < 8; ++mi)
#pragma unroll
    for (int ni = 0; ni < 4; ++ni)
#pragma unroll
      for (int r = 0; r < 4; ++r) {
        int row = wm + mi * 16 + q4 + r;
        int col = wn + ni * 16 + l15;
        float v = acc[mi][ni][r] + bias[ni];
        hrow[(size_t)row * DFFD + col] = (_Float16)gelu_f(v);
      }
}

// ---------------- GEMM2: final[tok] = (h @ W2 + b2) * gate ----------------
// (R4-verified 128² core kept: at 256x128 gemm2's grid would be 320 blocks
// on 512 slots -> 2-vs-1 residency imbalance, worse makespan than 640/768.)
__global__ __launch_bounds__(256, 3) void gemm2_kernel(
    const _Float16* __restrict__ hb, const _Float16* __restrict__ w2t,
    const float* __restrict__ b2, const int* __restrict__ s2t,
    const float* __restrict__ gatef, float* __restrict__ outp) {
  __shared__ __align__(16) _Float16 buf[24576];  // 48 KB 3-slot ring
  __shared__ int tok_s[128];
  __shared__ float gate_s[128];
  // XCD-aware bijective swizzle (grid = 640 = 8*80; one expert per XCD)
  int nwg = gridDim.x;
  int bx = blockIdx.x;
  int blk = (bx & 7) * (nwg >> 3) + (bx >> 3);
  int e = blk / 80;
  int rem = blk % 80;
  int mb = rem / 8, nb = rem % 8;
  int tid = threadIdx.x;
  if (tid < 128) {
    int tok = s2t[e * CAPD + mb * 128 + tid];
    tok_s[tid] = tok;
    gate_s[tid] = (tok < NTOK) ? gatef[tok] : 0.f;
  }
  __syncthreads();  // drains all vmem before the counted-vmcnt core
  const _Float16* A = hb + (size_t)e * CAPD * DFFD + (size_t)mb * 128 * DFFD;
  const _Float16* B = w2t + (size_t)e * DIMD * DFFD + (size_t)nb * 128 * DFFD;
  float4_t acc[4][4];
#pragma unroll
  for (int mi = 0; mi < 4; ++mi)
#pragma unroll
    for (int ni = 0; ni < 4; ++ni) acc[mi][ni] = (float4_t){0.f, 0.f, 0.f, 0.f};
  gemm_core128<DFFD>(A, B, buf, acc);
  const int lane = tid & 63;
  const int wid = tid >> 6;
  const int wm = (wid >> 1) * 64, wn = (wid & 1) * 64;
  const int l15 = lane & 15, q4 = (lane >> 4) * 4;
  float bias[4];
#pragma unroll
  for (int ni = 0; ni < 4; ++ni) bias[ni] = b2[e * DIMD + nb * 128 + wn + ni * 16 + l15];
#pragma unroll
  for (int mi = 0; mi < 4; ++mi)
#pragma unroll
    for (int r = 0; r < 4; ++r) {
      int row = wm + mi * 16 + q4 + r;
      int tok = tok_s[row];
      float g = gate_s[row];
      if (tok < NTOK) {
#pragma unroll
        for (int ni = 0; ni < 4; ++ni) {
          int col = nb * 128 + wn + ni * 16 + l15;
          outp[(size_t)tok * DIMD + col] = (acc[mi][ni][r] + bias[ni]) * g;
        }
      }
    }
}

extern "C" void kernel_launch(void* const* d_in, const int* in_sizes, int n_in,
                              void* d_out, int out_size, void* d_ws, size_t ws_size,
                              hipStream_t stream) {
  const float* x  = (const float*)d_in[0];
  const float* Wr = (const float*)d_in[1];
  const float* W1 = (const float*)d_in[2];
  const float* b1 = (const float*)d_in[3];
  const float* W2 = (const float*)d_in[4];
  const float* b2 = (const float*)d_in[5];
  float* out = (float*)d_out;

  char* ws = (char*)d_ws;
  float* probs_tok = (float*)ws;                        // 256 KB
  int* eidx   = (int*)(ws + 262144);                    // 32 KB
  float* gate = (float*)(ws + 262144 + 32768);          // 32 KB
  float* gatef = (float*)(ws + 262144 + 65536);         // 32 KB
  int* s2t    = (int*)(ws + 262144 + 98304);            // 40 KB
  int* kept   = (int*)(ws + 262144 + 139264);           // 32 KB
  char* big = ws + 448 * 1024;

  const size_t MB = 1024 * 1024;
  _Float16* gxb = (_Float16*)big;                       // 20 MiB
  _Float16* w1t = (_Float16*)(big + 20 * MB);           // 64 MiB
  // Overlapped path needs a separate 64 MiB w2t so the W2 transpose can run
  // concurrently with gemm1. Fallback aliases w2t=w1t, sequential transpose.
  size_t need = 448 * 1024 + (20 + 64 + 64 + 80) * MB;
  bool overlap = (ws_size >= need);
  _Float16* w2t = overlap ? (_Float16*)(big + 84 * MB) : w1t;
  _Float16* hb  = overlap ? (_Float16*)(big + 148 * MB)
                          : (_Float16*)(big + 84 * MB); // 80 MiB

  const int NG1 = NEXP * 5 * 32;    // 1280 gemm1 blocks (256x128 tiles)
  const int NTR = NEXP * 16 * 64;   // 8192 transpose tiles

  router_kernel<<<NTOK / 4, 256, 0, stream>>>(x, Wr, eidx, gate, probs_tok);
  // scan (1 block) + W1 transpose (8192 blocks) in one launch
  scan_w1t_kernel<<<1 + NTR, 256, 0, stream>>>(
      eidx, gate, probs_tok, gatef, s2t, kept, out + (size_t)NTOK * DIMD,
      W1, w1t);
  // gather (10240) + passthrough (8192)
  gp_kernel<<<NEXP * CAPD + NTOK, 256, 0, stream>>>(x, s2t, kept, gxb, out);
  if (overlap) {
    gemm1_kernel<<<NG1 + NTR, 256, 0, stream>>>(gxb, w1t, b1, hb, W2, w2t, NG1);
  } else {
    gemm1_kernel<<<NG1, 256, 0, stream>>>(gxb, w1t, b1, hb, W2, w2t, NG1);
    transpose_cvt_kernel<<<NTR, 256, 0, stream>>>(W2, w2t, DFFD, DIMD);
  }
  gemm2_kernel<<<NEXP * 10 * 8, 256, 0, stream>>>(hb, w2t, b2, s2t, gatef, out);
}